// Round 1
// baseline (3320.863 us; speedup 1.0000x reference)
//
#include <hip/hip_runtime.h>
#include <stdint.h>

// Problem constants
#define FD 1024          // feature dim (K)
#define NC 8192          // classes per view
#define NT 16384         // N = 2*NC
#define BM 64            // rows per block (A-panel in LDS)
#define BN 128           // cols per j-tile
#define BK 64            // k per staged B-tile
#define NJT (NT / BN)    // 128 j-tiles
#define NKT (FD / BK)    // 16 k-steps

typedef __attribute__((ext_vector_type(8))) short bf16x8;
typedef __attribute__((ext_vector_type(4))) float f32x4;

__device__ __forceinline__ unsigned short f2bf(float f) {
  unsigned u = __float_as_uint(f);
  u += 0x7FFF + ((u >> 16) & 1);   // RNE
  return (unsigned short)(u >> 16);
}
__device__ __forceinline__ float bf2f(unsigned short s) {
  return __uint_as_float(((unsigned)s) << 16);
}

// ---------------------------------------------------------------------------
// Kernel T: h_i,h_j [1024][8192] fp32 -> HT [16384][1024] bf16 (transposed)
// ---------------------------------------------------------------------------
__global__ void nt_xent_transpose(const float* __restrict__ hi,
                                  const float* __restrict__ hj,
                                  unsigned short* __restrict__ HT) {
  __shared__ unsigned short tile[64][65];   // +1 pad vs bank conflicts
  const int bn = blockIdx.x;                // n-tile: 0..255
  const int bd = blockIdx.y;                // d-tile: 0..15
  const int n0 = bn * 64, d0 = bd * 64;
  const float* src = (n0 < NC) ? hi : hj;
  const int nb = (n0 < NC) ? n0 : n0 - NC;
  const int tid = threadIdx.x;
#pragma unroll
  for (int i = 0; i < 16; ++i) {
    int idx = tid + 256 * i;                // 4096 elements
    int dl = idx >> 6, nl = idx & 63;       // coalesced read along n
    float f = src[(size_t)(d0 + dl) * NC + nb + nl];
    tile[nl][dl] = f2bf(f);
  }
  __syncthreads();
#pragma unroll
  for (int i = 0; i < 16; ++i) {
    int idx = tid + 256 * i;
    int nl = idx >> 6, dl = idx & 63;       // coalesced write along d
    HT[(size_t)(n0 + nl) * FD + d0 + dl] = tile[nl][dl];
  }
}

// ---------------------------------------------------------------------------
// Kernel G: fused SYRK + online row-logsumexp.
// Block = 64 rows, full j-sweep. A-panel [64][1024] bf16 resident in LDS.
// B-tiles [128][64] streamed with register prefetch. XOR-swizzled 16B slots.
// MFMA 16x16x32 bf16; C/D layout: col=lane&15, row=4*(lane>>4)+reg (verified).
// ---------------------------------------------------------------------------
__global__ __launch_bounds__(256, 1)
void nt_xent_gemm_lse(const unsigned short* __restrict__ HT,
                      float* __restrict__ lse) {
  __shared__ __align__(16) unsigned short Apan[BM * FD];   // 128 KB
  __shared__ __align__(16) unsigned short Bt[BN * BK];     // 16 KB
  __shared__ float red[4][BM][2];                          // 2 KB

  const int tid = threadIdx.x;
  const int w = tid >> 6;        // wave 0..3 -> 32-col stripe
  const int l = tid & 63;
  const int r0 = blockIdx.x * BM;

  // ---- stage A panel (once): 8192 16B chunks, swizzle slot ^= (row&7) ----
#pragma unroll
  for (int i = 0; i < 32; ++i) {
    int c = tid + 256 * i;                  // 0..8191
    int r = c >> 7, s = c & 127;            // row, 16B-slot (128 slots/row)
    int4 v = *(const int4*)(HT + (((size_t)(r0 + r)) << 10) + (s << 3));
    *(int4*)(Apan + r * FD + ((s ^ (r & 7)) << 3)) = v;
  }
  // ---- stage B tile for t=0 (jt=0, kt=0) ----
#pragma unroll
  for (int i = 0; i < 4; ++i) {
    int c = tid + 256 * i;                  // 0..1023
    int row = c >> 3, s = c & 7;
    int4 v = *(const int4*)(HT + (((size_t)row) << 10) + (s << 3));
    *(int4*)(Bt + row * BK + ((s ^ (row & 7)) << 3)) = v;
  }
  __syncthreads();

  // per-lane online LSE state: 16 (m,s) pairs (4 m-frags x 4 regs)
  float mst[4][4], sst[4][4];
#pragma unroll
  for (int a = 0; a < 4; ++a)
#pragma unroll
    for (int b = 0; b < 4; ++b) { mst[a][b] = -INFINITY; sst[a][b] = 0.f; }

  f32x4 acc[4][2];
#pragma unroll
  for (int a = 0; a < 4; ++a)
#pragma unroll
    for (int b = 0; b < 2; ++b) acc[a][b] = (f32x4){0.f, 0.f, 0.f, 0.f};

  const int TT = NJT * NKT;  // 2048
  for (int t = 0; t < TT; ++t) {
    const int jt = t >> 4, kt = t & 15;

    // prefetch next B tile into registers (hidden under MFMA below)
    int4 pf[4];
    if (t + 1 < TT) {
      int tn = t + 1, jn = tn >> 4, kn = tn & 15;
      int cb = jn * BN;
#pragma unroll
      for (int i = 0; i < 4; ++i) {
        int c = tid + 256 * i;
        int row = c >> 3, s = c & 7;
        pf[i] = *(const int4*)(HT + (((size_t)(cb + row)) << 10) + (kn << 6) + (s << 3));
      }
    }

    // fragment loads (swizzled) + 16 MFMAs
    bf16x8 af[4][2], bfr[2][2];
#pragma unroll
    for (int mi = 0; mi < 4; ++mi) {
      int r = mi * 16 + (l & 15);
#pragma unroll
      for (int kk = 0; kk < 2; ++kk) {
        int s = kt * 8 + kk * 4 + (l >> 4);
        af[mi][kk] = *(const bf16x8*)(Apan + r * FD + ((s ^ (r & 7)) << 3));
      }
    }
#pragma unroll
    for (int ni = 0; ni < 2; ++ni) {
      int col = w * 32 + ni * 16 + (l & 15);
#pragma unroll
      for (int kk = 0; kk < 2; ++kk) {
        int s = kk * 4 + (l >> 4);
        bfr[ni][kk] = *(const bf16x8*)(Bt + col * BK + ((s ^ (col & 7)) << 3));
      }
    }
#pragma unroll
    for (int kk = 0; kk < 2; ++kk)
#pragma unroll
      for (int mi = 0; mi < 4; ++mi)
#pragma unroll
        for (int ni = 0; ni < 2; ++ni)
          acc[mi][ni] = __builtin_amdgcn_mfma_f32_16x16x32_bf16(
              af[mi][kk], bfr[ni][kk], acc[mi][ni], 0, 0, 0);

    // tile finished (all K)? -> per-lane online logsumexp update, no shuffles
    if (kt == 15) {
      const int gcol0 = jt * BN + w * 32 + (l & 15);   // col of ni=0 element
#pragma unroll
      for (int mi = 0; mi < 4; ++mi) {
        int growb = r0 + mi * 16 + ((l >> 4) << 2);
#pragma unroll
        for (int rg = 0; rg < 4; ++rg) {
          int grow = growb + rg;
          float v0 = acc[mi][0][rg] * 2.0f;            // 1/T = 2
          float v1 = acc[mi][1][rg] * 2.0f;
          if (gcol0 == grow)      v0 = -INFINITY;      // mask diagonal
          if (gcol0 + 16 == grow) v1 = -INFINITY;
          float mx = fmaxf(v0, v1);                    // finite always
          float mo = mst[mi][rg];
          float mn = fmaxf(mo, mx);
          sst[mi][rg] = sst[mi][rg] * __expf(mo - mn) + __expf(v0 - mn) + __expf(v1 - mn);
          mst[mi][rg] = mn;
          acc[mi][0][rg] = 0.f;
          acc[mi][1][rg] = 0.f;
        }
      }
    }

    __syncthreads();
    if (t + 1 < TT) {
#pragma unroll
      for (int i = 0; i < 4; ++i) {
        int c = tid + 256 * i;
        int row = c >> 3, s = c & 7;
        *(int4*)(Bt + row * BK + ((s ^ (row & 7)) << 3)) = pf[i];
      }
    }
    __syncthreads();
  }

  // ---- merge (m,s) across the 16 lanes of each quarter-group ----
#pragma unroll
  for (int mi = 0; mi < 4; ++mi)
#pragma unroll
    for (int rg = 0; rg < 4; ++rg) {
      float m = mst[mi][rg], s = sst[mi][rg];
#pragma unroll
      for (int off = 1; off < 16; off <<= 1) {
        float m2 = __shfl_xor(m, off, 16);
        float s2 = __shfl_xor(s, off, 16);
        float mn = fmaxf(m, m2);
        s = s * __expf(m - mn) + s2 * __expf(m2 - mn);
        m = mn;
      }
      if ((l & 15) == 0) {
        int row = mi * 16 + ((l >> 4) << 2) + rg;
        red[w][row][0] = m;
        red[w][row][1] = s;
      }
    }
  __syncthreads();

  // ---- merge across 4 waves, write lse ----
  if (tid < BM) {
    float M = -INFINITY;
#pragma unroll
    for (int ww = 0; ww < 4; ++ww) M = fmaxf(M, red[ww][tid][0]);
    float S = 0.f;
#pragma unroll
    for (int ww = 0; ww < 4; ++ww) S += red[ww][tid][1] * __expf(red[ww][tid][0] - M);
    lse[r0 + tid] = M + __logf(S);
  }
}

// ---------------------------------------------------------------------------
// Kernel P: pos = 2*dot(HT[i], HT[(i+NC)%NT]); out += (lse[i]-pos)/NT
// ---------------------------------------------------------------------------
__global__ void nt_xent_pos_reduce(const unsigned short* __restrict__ HT,
                                   const float* __restrict__ lse,
                                   float* __restrict__ out) {
  const int tid = threadIdx.x;
  const int w = tid >> 6, l = tid & 63;
  const int wave = blockIdx.x * 4 + w;      // 0..1023, 16 rows each
  float local = 0.f;
  for (int rr = 0; rr < 16; ++rr) {
    int i = wave * 16 + rr;
    int p = (i + NC) & (NT - 1);
    const int4* A = (const int4*)(HT + (((size_t)i) << 10) + (l << 4));
    const int4* B = (const int4*)(HT + (((size_t)p) << 10) + (l << 4));
    union { int4 v; unsigned short u[8]; } a0, a1, b0, b1;
    a0.v = A[0]; a1.v = A[1]; b0.v = B[0]; b1.v = B[1];
    float dot = 0.f;
#pragma unroll
    for (int j = 0; j < 8; ++j) dot += bf2f(a0.u[j]) * bf2f(b0.u[j]);
#pragma unroll
    for (int j = 0; j < 8; ++j) dot += bf2f(a1.u[j]) * bf2f(b1.u[j]);
#pragma unroll
    for (int off = 1; off < 64; off <<= 1) dot += __shfl_xor(dot, off, 64);
    if (l == 0) local += lse[i] - 2.0f * dot;
  }
  if (l == 0) atomicAdd(out, local * (1.0f / (float)NT));
}

// ---------------------------------------------------------------------------
extern "C" void kernel_launch(void* const* d_in, const int* in_sizes, int n_in,
                              void* d_out, int out_size, void* d_ws, size_t ws_size,
                              hipStream_t stream) {
  const float* hi = (const float*)d_in[0];
  const float* hj = (const float*)d_in[1];
  unsigned short* HT = (unsigned short*)d_ws;
  float* lsebuf = (float*)((char*)d_ws + (size_t)NT * FD * 2);
  float* out = (float*)d_out;

  const size_t need = (size_t)NT * FD * 2 + (size_t)NT * 4;
  if (ws_size < need) return;   // workspace too small: bail (will fail check)

  hipMemsetAsync(out, 0, sizeof(float), stream);
  nt_xent_transpose<<<dim3(NT / 64, FD / 64), 256, 0, stream>>>(hi, hj, HT);
  nt_xent_gemm_lse<<<NT / BM, 256, 0, stream>>>(HT, lsebuf);
  nt_xent_pos_reduce<<<NT / 64, 256, 0, stream>>>(HT, lsebuf, out);
}

// Round 2
// 1722.775 us; speedup vs baseline: 1.9276x; 1.9276x over previous
//
#include <hip/hip_runtime.h>
#include <stdint.h>

// Problem constants
#define FD 1024          // feature dim (K)
#define NC 8192          // classes per view
#define NT 16384         // N = 2*NC
#define BM 64            // rows per block (A-panel in LDS)
#define BN 128           // cols per j-tile
#define BK 64            // k per staged B-tile
#define NJT (NT / BN)    // 128 j-tiles
#define NKT (FD / BK)    // 16 k-steps
#define TT (NJT * NKT)   // 2048 iterations

typedef __attribute__((ext_vector_type(8))) short bf16x8;
typedef __attribute__((ext_vector_type(4))) float f32x4;

__device__ __forceinline__ unsigned short f2bf(float f) {
  unsigned u = __float_as_uint(f);
  u += 0x7FFF + ((u >> 16) & 1);   // RNE
  return (unsigned short)(u >> 16);
}
__device__ __forceinline__ float bf2f(unsigned short s) {
  return __uint_as_float(((unsigned)s) << 16);
}

// async global->LDS, 16B per lane; LDS dest must be wave-uniform (HW adds lane*16)
__device__ __forceinline__ void gld16(const void* g, void* l) {
  __builtin_amdgcn_global_load_lds(
      (const __attribute__((address_space(1))) unsigned int*)g,
      (__attribute__((address_space(3))) unsigned int*)l, 16, 0, 0);
}

// ---------------------------------------------------------------------------
// Kernel T: h_i,h_j [1024][8192] fp32 -> HT [16384][1024] bf16 (transposed)
// ---------------------------------------------------------------------------
__global__ void nt_xent_transpose(const float* __restrict__ hi,
                                  const float* __restrict__ hj,
                                  unsigned short* __restrict__ HT) {
  __shared__ unsigned short tile[64][65];
  const int bn = blockIdx.x;                // n-tile: 0..255
  const int bd = blockIdx.y;                // d-tile: 0..15
  const int n0 = bn * 64, d0 = bd * 64;
  const float* src = (n0 < NC) ? hi : hj;
  const int nb = (n0 < NC) ? n0 : n0 - NC;
  const int tid = threadIdx.x;
#pragma unroll
  for (int i = 0; i < 16; ++i) {
    int idx = tid + 256 * i;
    int dl = idx >> 6, nl = idx & 63;       // coalesced read along n
    float f = src[(size_t)(d0 + dl) * NC + nb + nl];
    tile[nl][dl] = f2bf(f);
  }
  __syncthreads();
#pragma unroll
  for (int i = 0; i < 16; ++i) {
    int idx = tid + 256 * i;
    int nl = idx >> 6, dl = idx & 63;       // coalesced write along d
    HT[(size_t)(n0 + nl) * FD + d0 + dl] = tile[nl][dl];
  }
}

// ---------------------------------------------------------------------------
// Kernel G: fused SYRK + online row-logsumexp.
//   A-panel [64 rows][1024 k] resident in LDS, FRAG-LINEAR layout:
//     frag g=((kt*2+kk)*4+mi): 1KB slot, lane l holds
//     row=mi*16+(l&15), k=kt*64+kk*32+(l>>4)*8 .. +8    (same bytes as R0)
//   B tiles [128 cols][64 k] double-buffered via global_load_lds, frag-linear:
//     frag f=((kk*4+wv)*2+ni): col=wv*32+ni*16+(l&15), k=kk*32+(l>>4)*8
//   One barrier per iteration (stage next -> compute cur -> barrier).
// ---------------------------------------------------------------------------
__global__ __launch_bounds__(256, 1)
void nt_xent_gemm_lse(const unsigned short* __restrict__ HT,
                      float* __restrict__ lse) {
  __shared__ __align__(16) unsigned char lds[163840];   // 160 KiB exactly
  unsigned char* Abuf = lds;                            // 128 KB
  // B buffers at 131072 + cur*16384 (16 KB each)
  float (*red)[BM][2] = (float (*)[BM][2])(lds + 131072);  // overlay, used post-loop

  const int tid = threadIdx.x;
  const int w = tid >> 6;        // wave 0..3 -> 32-col stripe
  const int l = tid & 63;
  const int r0 = blockIdx.x * BM;
  const int lr = l & 15;         // row/col within fragment
  const int lk = (l >> 4) * 8;   // k-offset (shorts) within 32-slice

  // ---- stage A panel: 32 gload_lds per wave, frag-linear, zero conflicts ----
#pragma unroll
  for (int i = 0; i < 32; ++i) {
    int g = 4 * i + w;                         // frag 0..127 (uniform per wave)
    int kt = g >> 3, kk = (g >> 2) & 1, mi = g & 3;
    int row = r0 + mi * 16 + lr;
    int k = kt * 64 + kk * 32 + lk;
    gld16(HT + (((size_t)row) << 10) + k, Abuf + g * 1024);
  }
  // ---- stage B tile for t=0 (jt=0, kt=0) ----
#pragma unroll
  for (int q = 0; q < 4; ++q) {
    int f = w * 4 + q;                         // frag 0..15 (uniform per wave)
    int kk = f >> 3, wv = (f >> 1) & 3, ni = f & 1;
    int col = wv * 32 + ni * 16 + lr;
    int k = kk * 32 + lk;
    gld16(HT + (((size_t)col) << 10) + k, lds + 131072 + f * 1024);
  }
  __syncthreads();   // compiler drains vmcnt+lgkmcnt before s_barrier

  float mst[4][4], sst[4][4];
#pragma unroll
  for (int a = 0; a < 4; ++a)
#pragma unroll
    for (int b = 0; b < 4; ++b) { mst[a][b] = -INFINITY; sst[a][b] = 0.f; }

  f32x4 acc[4][2];
#pragma unroll
  for (int a = 0; a < 4; ++a)
#pragma unroll
    for (int b = 0; b < 2; ++b) acc[a][b] = (f32x4){0.f, 0.f, 0.f, 0.f};

  const unsigned char* Afl = Abuf + l * 16;    // per-lane A fragment base

  for (int t = 0; t < TT; ++t) {
    const int jt = t >> 4, kt = t & 15;
    const int cur = t & 1;

    // ---- issue next B-tile stage FIRST (latency hides under compute) ----
    {
      int tn = (t + 1) & (TT - 1);             // wrap: last iter stages tile 0 (discarded)
      int jn = tn >> 4, kn = tn & 15;
      unsigned char* Bdst = lds + 131072 + (cur ^ 1) * 16384;
#pragma unroll
      for (int q = 0; q < 4; ++q) {
        int f = w * 4 + q;
        int kk = f >> 3, wv = (f >> 1) & 3, ni = f & 1;
        int col = jn * BN + wv * 32 + ni * 16 + lr;
        int k = kn * 64 + kk * 32 + lk;
        gld16(HT + (((size_t)col) << 10) + k, Bdst + f * 1024);
      }
    }

    // ---- fragment reads: all ds_read_b128 at lane*16 + imm (conflict-free) ----
    const unsigned char* Ab = Afl + kt * 8192;
    const unsigned char* Bb = lds + 131072 + cur * 16384 + w * 2048 + l * 16;
    bf16x8 af[2][4], bfr[2][2];
#pragma unroll
    for (int kk = 0; kk < 2; ++kk) {
#pragma unroll
      for (int mi = 0; mi < 4; ++mi)
        af[kk][mi] = *(const bf16x8*)(Ab + (kk * 4 + mi) * 1024);
#pragma unroll
      for (int ni = 0; ni < 2; ++ni)
        bfr[kk][ni] = *(const bf16x8*)(Bb + kk * 8192 + ni * 1024);
    }
#pragma unroll
    for (int kk = 0; kk < 2; ++kk)
#pragma unroll
      for (int mi = 0; mi < 4; ++mi)
#pragma unroll
        for (int ni = 0; ni < 2; ++ni)
          acc[mi][ni] = __builtin_amdgcn_mfma_f32_16x16x32_bf16(
              af[kk][mi], bfr[kk][ni], acc[mi][ni], 0, 0, 0);

    // ---- tile complete: per-lane online logsumexp update ----
    if (kt == 15) {
      const int gcol0 = jt * BN + w * 32 + lr;      // col of ni=0 element
#pragma unroll
      for (int mi = 0; mi < 4; ++mi) {
        int growb = r0 + mi * 16 + ((l >> 4) << 2);
#pragma unroll
        for (int rg = 0; rg < 4; ++rg) {
          int grow = growb + rg;
          float v0 = acc[mi][0][rg] * 2.0f;         // 1/T = 2
          float v1 = acc[mi][1][rg] * 2.0f;
          if (gcol0 == grow)      v0 = -INFINITY;   // mask diagonal
          if (gcol0 + 16 == grow) v1 = -INFINITY;
          float mx = fmaxf(v0, v1);
          float mo = mst[mi][rg];
          float mn = fmaxf(mo, mx);
          sst[mi][rg] = sst[mi][rg] * __expf(mo - mn) + __expf(v0 - mn) + __expf(v1 - mn);
          mst[mi][rg] = mn;
          acc[mi][0][rg] = 0.f;
          acc[mi][1][rg] = 0.f;
        }
      }
    }

    __syncthreads();   // single barrier: drains staging vmcnt + frag lgkmcnt
  }

  // ---- merge (m,s) across the 16 lanes sharing each row ----
#pragma unroll
  for (int mi = 0; mi < 4; ++mi)
#pragma unroll
    for (int rg = 0; rg < 4; ++rg) {
      float m = mst[mi][rg], s = sst[mi][rg];
#pragma unroll
      for (int off = 1; off < 16; off <<= 1) {
        float m2 = __shfl_xor(m, off, 16);
        float s2 = __shfl_xor(s, off, 16);
        float mn = fmaxf(m, m2);
        s = s * __expf(m - mn) + s2 * __expf(m2 - mn);
        m = mn;
      }
      if (lr == 0) {
        int row = mi * 16 + ((l >> 4) << 2) + rg;
        red[w][row][0] = m;
        red[w][row][1] = s;
      }
    }
  __syncthreads();

  // ---- merge across 4 waves, write lse ----
  if (tid < BM) {
    float M = -INFINITY;
#pragma unroll
    for (int ww = 0; ww < 4; ++ww) M = fmaxf(M, red[ww][tid][0]);
    float S = 0.f;
#pragma unroll
    for (int ww = 0; ww < 4; ++ww) S += red[ww][tid][1] * __expf(red[ww][tid][0] - M);
    lse[r0 + tid] = M + __logf(S);
  }
}

// ---------------------------------------------------------------------------
// Kernel P: pos = 2*dot(HT[i], HT[(i+NC)%NT]); out += (lse[i]-pos)/NT
// ---------------------------------------------------------------------------
__global__ void nt_xent_pos_reduce(const unsigned short* __restrict__ HT,
                                   const float* __restrict__ lse,
                                   float* __restrict__ out) {
  const int tid = threadIdx.x;
  const int w = tid >> 6, l = tid & 63;
  const int wave = blockIdx.x * 4 + w;      // 0..1023, 16 rows each
  float local = 0.f;
  for (int rr = 0; rr < 16; ++rr) {
    int i = wave * 16 + rr;
    int p = (i + NC) & (NT - 1);
    const int4* A = (const int4*)(HT + (((size_t)i) << 10) + (l << 4));
    const int4* B = (const int4*)(HT + (((size_t)p) << 10) + (l << 4));
    union { int4 v; unsigned short u[8]; } a0, a1, b0, b1;
    a0.v = A[0]; a1.v = A[1]; b0.v = B[0]; b1.v = B[1];
    float dot = 0.f;
#pragma unroll
    for (int j = 0; j < 8; ++j) dot += bf2f(a0.u[j]) * bf2f(b0.u[j]);
#pragma unroll
    for (int j = 0; j < 8; ++j) dot += bf2f(a1.u[j]) * bf2f(b1.u[j]);
#pragma unroll
    for (int off = 1; off < 64; off <<= 1) dot += __shfl_xor(dot, off, 64);
    if (l == 0) local += lse[i] - 2.0f * dot;
  }
  if (l == 0) atomicAdd(out, local * (1.0f / (float)NT));
}

// ---------------------------------------------------------------------------
extern "C" void kernel_launch(void* const* d_in, const int* in_sizes, int n_in,
                              void* d_out, int out_size, void* d_ws, size_t ws_size,
                              hipStream_t stream) {
  const float* hi = (const float*)d_in[0];
  const float* hj = (const float*)d_in[1];
  unsigned short* HT = (unsigned short*)d_ws;
  float* lsebuf = (float*)((char*)d_ws + (size_t)NT * FD * 2);
  float* out = (float*)d_out;

  const size_t need = (size_t)NT * FD * 2 + (size_t)NT * 4;
  if (ws_size < need) return;

  hipMemsetAsync(out, 0, sizeof(float), stream);
  nt_xent_transpose<<<dim3(NT / 64, FD / 64), 256, 0, stream>>>(hi, hj, HT);
  nt_xent_gemm_lse<<<NT / BM, 256, 0, stream>>>(HT, lsebuf);
  nt_xent_pos_reduce<<<NT / 64, 256, 0, stream>>>(HT, lsebuf, out);
}

// Round 3
// 1028.973 us; speedup vs baseline: 3.2274x; 1.6743x over previous
//
#include <hip/hip_runtime.h>
#include <stdint.h>

// Problem constants
#define FD 1024          // feature dim (K)
#define NC 8192          // classes per view
#define NT 16384         // N = 2*NC
#define BT 128           // block tile (rows == cols)
#define BK 64            // k per staged step
#define NKT (FD / BK)    // 16 k-steps

typedef __attribute__((ext_vector_type(8))) short bf16x8;
typedef __attribute__((ext_vector_type(4))) float f32x4;

__device__ __forceinline__ unsigned short f2bf(float f) {
  unsigned u = __float_as_uint(f);
  u += 0x7FFF + ((u >> 16) & 1);   // RNE
  return (unsigned short)(u >> 16);
}
__device__ __forceinline__ float bf2f(unsigned short s) {
  return __uint_as_float(((unsigned)s) << 16);
}

// async global->LDS, 16B/lane; LDS dest wave-uniform (HW adds lane*16)
__device__ __forceinline__ void gld16(const void* g, void* l) {
  __builtin_amdgcn_global_load_lds(
      (const __attribute__((address_space(1))) unsigned int*)g,
      (__attribute__((address_space(3))) unsigned int*)l, 16, 0, 0);
}

// online-LSE merge of (m2,s2) into packed global state {lo: m bits, hi: s bits}
__device__ __forceinline__ void cas_merge(unsigned long long* p, float m2, float s2) {
  unsigned long long old = *p, assumed;
  do {
    assumed = old;
    float m1 = __uint_as_float((unsigned)(assumed & 0xffffffffull));
    float s1 = __uint_as_float((unsigned)(assumed >> 32));
    float mn = fmaxf(m1, m2);                       // m2 always finite
    float s = s1 * __expf(m1 - mn) + s2 * __expf(m2 - mn);
    unsigned long long nv =
        ((unsigned long long)__float_as_uint(s) << 32) | __float_as_uint(mn);
    old = atomicCAS(p, assumed, nv);
  } while (old != assumed);
}

// ---------------------------------------------------------------------------
// Kernel I: init global (m,s) state to (-inf, 0)
// ---------------------------------------------------------------------------
__global__ void nt_xent_init(unsigned long long* __restrict__ G) {
  G[blockIdx.x * 256 + threadIdx.x] = 0xFF800000ull;  // m=-inf, s=0
}

// ---------------------------------------------------------------------------
// Kernel T: h_i,h_j [1024][8192] fp32 -> HT [16384][1024] bf16 (transposed)
// ---------------------------------------------------------------------------
__global__ void nt_xent_transpose(const float* __restrict__ hi,
                                  const float* __restrict__ hj,
                                  unsigned short* __restrict__ HT) {
  __shared__ unsigned short tile[64][65];
  const int bn = blockIdx.x;                // n-tile: 0..255
  const int bd = blockIdx.y;                // d-tile: 0..15
  const int n0 = bn * 64, d0 = bd * 64;
  const float* src = (n0 < NC) ? hi : hj;
  const int nb = (n0 < NC) ? n0 : n0 - NC;
  const int tid = threadIdx.x;
#pragma unroll
  for (int i = 0; i < 16; ++i) {
    int idx = tid + 256 * i;
    int dl = idx >> 6, nl = idx & 63;       // coalesced read along n
    float f = src[(size_t)(d0 + dl) * NC + nb + nl];
    tile[nl][dl] = f2bf(f);
  }
  __syncthreads();
#pragma unroll
  for (int i = 0; i < 16; ++i) {
    int idx = tid + 256 * i;
    int nl = idx >> 6, dl = idx & 63;       // coalesced write along d
    HT[(size_t)(n0 + nl) * FD + d0 + dl] = tile[nl][dl];
  }
}

// ---------------------------------------------------------------------------
// Kernel G: 128x128-tile GEMM (m97 structure) + per-tile row-LSE partial
//   Grid: 128x128 = 16384 blocks, XCD-swizzled, 8x8 supertiles for L2.
//   4 waves (2x2), each computes 64x64 (4x4 frags 16x16x32 bf16, K=1024).
//   LDS 32 KB: A[16 frags][1KB] + B[16 frags][1KB], frag-linear, single-buf,
//   2 barriers per k-step; 3 blocks/CU (launch_bounds 256,3) give the TLP.
//   Frag (kk,idx): lane l holds row/col = idx*16+(l&15), k = kk*32+(l>>4)*8.
//   C/D layout (verified): col = lane&15, row = (lane>>4)*4 + reg.
//   Epilogue: per-row (m,s) over the tile's 128 cols -> CAS-merge into G.
// ---------------------------------------------------------------------------
__global__ __launch_bounds__(256, 3)
void nt_xent_gemm_lse(const unsigned short* __restrict__ HT,
                      unsigned long long* __restrict__ G) {
  __shared__ __align__(16) unsigned char lds[32768];
  unsigned char* Abuf = lds;            // 16 KB
  unsigned char* Bbuf = lds + 16384;    // 16 KB
  float (*red)[2][64][2] = (float (*)[2][64][2])lds;  // overlay post-loop

  const int tid = threadIdx.x;
  const int w = tid >> 6, l = tid & 63;
  const int lr = l & 15;                // row/col within fragment
  const int lk = (l >> 4) * 8;          // k-offset (shorts) within 32-slice
  const int wr = w >> 1, wc = w & 1;    // wave -> 64x64 quadrant

  // bijective XCD swizzle + 8x8 supertiles (4 MB A+B panels per supertile)
  const int bid = blockIdx.x;
  const int xcd = bid & 7, pos = bid >> 3;     // chunk position 0..2047
  const int st = pos >> 6, wi = pos & 63;      // supertile 0..31, within 0..63
  const int ti = xcd * 16 + (st & 1) * 8 + (wi & 7);
  const int tj = (st >> 1) * 8 + (wi >> 3);

  const unsigned short* Arows = HT + (((size_t)ti * BT) << 10);
  const unsigned short* Brows = HT + (((size_t)tj * BT) << 10);

  f32x4 acc[4][4];
#pragma unroll
  for (int a = 0; a < 4; ++a)
#pragma unroll
    for (int b = 0; b < 4; ++b) acc[a][b] = (f32x4){0.f, 0.f, 0.f, 0.f};

  for (int kt = 0; kt < NKT; ++kt) {
    __syncthreads();                    // prev step's frag reads complete
    const int kb = kt * 64;
    // ---- stage: 8 gload16 per wave; wave 0/1 -> A kk=0/1, wave 2/3 -> B ----
    if (w < 2) {
      const int kk = w;
#pragma unroll
      for (int q = 0; q < 8; ++q) {
        int row = q * 16 + lr;
        gld16(Arows + (((size_t)row) << 10) + kb + kk * 32 + lk,
              Abuf + (kk * 8 + q) * 1024);
      }
    } else {
      const int kk = w - 2;
#pragma unroll
      for (int q = 0; q < 8; ++q) {
        int col = q * 16 + lr;
        gld16(Brows + (((size_t)col) << 10) + kb + kk * 32 + lk,
              Bbuf + (kk * 8 + q) * 1024);
      }
    }
    __syncthreads();                    // drains vmcnt: tile ready

    // ---- frag reads (all ds_read_b128 at lane*16, conflict-free) + MFMA ----
    bf16x8 af[2][4], bf[2][4];
#pragma unroll
    for (int kk = 0; kk < 2; ++kk) {
#pragma unroll
      for (int m = 0; m < 4; ++m)
        af[kk][m] = *(const bf16x8*)(Abuf + (kk * 8 + wr * 4 + m) * 1024 + l * 16);
#pragma unroll
      for (int n = 0; n < 4; ++n)
        bf[kk][n] = *(const bf16x8*)(Bbuf + (kk * 8 + wc * 4 + n) * 1024 + l * 16);
    }
#pragma unroll
    for (int kk = 0; kk < 2; ++kk)
#pragma unroll
      for (int m = 0; m < 4; ++m)
#pragma unroll
        for (int n = 0; n < 4; ++n)
          acc[m][n] = __builtin_amdgcn_mfma_f32_16x16x32_bf16(
              af[kk][m], bf[kk][n], acc[m][n], 0, 0, 0);
  }

  __syncthreads();    // all frag reads done; safe to overlay red on Abuf

  // ---- per-row (m,s) over this tile's 128 cols ----
  const int gr0 = ti * BT + wr * 64 + ((l >> 4) << 2);  // + m*16 + rg
  const int gc0 = tj * BT + wc * 64 + lr;               // + n*16
#pragma unroll
  for (int m = 0; m < 4; ++m) {
#pragma unroll
    for (int rg = 0; rg < 4; ++rg) {
      const int grow = gr0 + m * 16 + rg;
      float vs[4], mx = -INFINITY;
#pragma unroll
      for (int n = 0; n < 4; ++n) {
        float v = acc[m][n][rg] * 2.0f;           // 1/T = 2
        if (gc0 + n * 16 == grow) v = -INFINITY;  // mask diagonal
        vs[n] = v;
        mx = fmaxf(mx, v);
      }
      float sm = 0.f;
#pragma unroll
      for (int n = 0; n < 4; ++n) sm += __expf(vs[n] - mx);
      // merge across the 16 lanes (lr) sharing these rows
#pragma unroll
      for (int off = 1; off < 16; off <<= 1) {
        float m2 = __shfl_xor(mx, off, 16);
        float s2 = __shfl_xor(sm, off, 16);
        float mn = fmaxf(mx, m2);
        sm = sm * __expf(mx - mn) + s2 * __expf(m2 - mn);
        mx = mn;
      }
      if (lr == 0) {
        const int rl = m * 16 + ((l >> 4) << 2) + rg;   // row-local 0..63
        red[wr][wc][rl][0] = mx;
        red[wr][wc][rl][1] = sm;
      }
    }
  }
  __syncthreads();

  // ---- combine wc halves, CAS-merge into global per-row state ----
  if (tid < 128) {
    const int wrr = tid >> 6, rl = tid & 63;
    float m0 = red[wrr][0][rl][0], s0 = red[wrr][0][rl][1];
    float m1 = red[wrr][1][rl][0], s1 = red[wrr][1][rl][1];
    float mn = fmaxf(m0, m1);
    float s = s0 * __expf(m0 - mn) + s1 * __expf(m1 - mn);
    cas_merge(&G[ti * BT + wrr * 64 + rl], mn, s);
  }
}

// ---------------------------------------------------------------------------
// Kernel F: lse[i] = m + log(s); pos = 2*dot(HT[i],HT[partner]);
//           out += (lse - pos)/NT
// ---------------------------------------------------------------------------
__global__ void nt_xent_final(const unsigned short* __restrict__ HT,
                              const unsigned long long* __restrict__ G,
                              float* __restrict__ out) {
  const int tid = threadIdx.x;
  const int w = tid >> 6, l = tid & 63;
  const int wave = blockIdx.x * 4 + w;      // 0..1023, 16 rows each
  float local = 0.f;
  for (int rr = 0; rr < 16; ++rr) {
    int i = wave * 16 + rr;
    int p = (i + NC) & (NT - 1);
    const int4* A = (const int4*)(HT + (((size_t)i) << 10) + (l << 4));
    const int4* B = (const int4*)(HT + (((size_t)p) << 10) + (l << 4));
    union { int4 v; unsigned short u[8]; } a0, a1, b0, b1;
    a0.v = A[0]; a1.v = A[1]; b0.v = B[0]; b1.v = B[1];
    float dot = 0.f;
#pragma unroll
    for (int j = 0; j < 8; ++j) dot += bf2f(a0.u[j]) * bf2f(b0.u[j]);
#pragma unroll
    for (int j = 0; j < 8; ++j) dot += bf2f(a1.u[j]) * bf2f(b1.u[j]);
#pragma unroll
    for (int off = 1; off < 64; off <<= 1) dot += __shfl_xor(dot, off, 64);
    if (l == 0) {
      unsigned long long g = G[i];
      float m = __uint_as_float((unsigned)(g & 0xffffffffull));
      float s = __uint_as_float((unsigned)(g >> 32));
      local += m + __logf(s) - 2.0f * dot;
    }
  }
  if (l == 0) atomicAdd(out, local * (1.0f / (float)NT));
}

// ---------------------------------------------------------------------------
extern "C" void kernel_launch(void* const* d_in, const int* in_sizes, int n_in,
                              void* d_out, int out_size, void* d_ws, size_t ws_size,
                              hipStream_t stream) {
  const float* hi = (const float*)d_in[0];
  const float* hj = (const float*)d_in[1];
  unsigned short* HT = (unsigned short*)d_ws;
  unsigned long long* G = (unsigned long long*)((char*)d_ws + (size_t)NT * FD * 2);
  float* out = (float*)d_out;

  const size_t need = (size_t)NT * FD * 2 + (size_t)NT * 8;
  if (ws_size < need) return;

  hipMemsetAsync(out, 0, sizeof(float), stream);
  nt_xent_init<<<NT / 256, 256, 0, stream>>>(G);
  nt_xent_transpose<<<dim3(NT / 64, FD / 64), 256, 0, stream>>>(hi, hj, HT);
  nt_xent_gemm_lse<<<16384, 256, 0, stream>>>(HT, G);
  nt_xent_final<<<NT / 64, 256, 0, stream>>>(HT, G, out);
}

// Round 4
// 746.146 us; speedup vs baseline: 4.4507x; 1.3791x over previous
//
#include <hip/hip_runtime.h>
#include <stdint.h>

// Problem constants
#define FD 1024          // feature dim (K)
#define NC 8192          // classes per view
#define NT 16384         // N = 2*NC
#define BT 128           // block tile (rows == cols)
#define BK 64            // k per staged step
#define NKT (FD / BK)    // 16 k-steps
#define NTILE 128        // tile-grid dimension (16384/128)
#define NTRI 8256        // NTILE*(NTILE+1)/2 upper-triangle tiles

typedef __attribute__((ext_vector_type(8))) short bf16x8;
typedef __attribute__((ext_vector_type(4))) float f32x4;

__device__ __forceinline__ unsigned short f2bf(float f) {
  unsigned u = __float_as_uint(f);
  u += 0x7FFF + ((u >> 16) & 1);   // RNE
  return (unsigned short)(u >> 16);
}
__device__ __forceinline__ float bf2f(unsigned short s) {
  return __uint_as_float(((unsigned)s) << 16);
}

// async global->LDS, 16B/lane; LDS dest wave-uniform (HW adds lane*16)
__device__ __forceinline__ void gld16(const void* g, void* l) {
  __builtin_amdgcn_global_load_lds(
      (const __attribute__((address_space(1))) unsigned int*)g,
      (__attribute__((address_space(3))) unsigned int*)l, 16, 0, 0);
}

// online-LSE merge of (m2,s2) into packed global state {lo: m bits, hi: s bits}
__device__ __forceinline__ void cas_merge(unsigned long long* p, float m2, float s2) {
  unsigned long long old = *p, assumed;
  do {
    assumed = old;
    float m1 = __uint_as_float((unsigned)(assumed & 0xffffffffull));
    float s1 = __uint_as_float((unsigned)(assumed >> 32));
    float mn = fmaxf(m1, m2);                       // m2 always finite
    float s = s1 * __expf(m1 - mn) + s2 * __expf(m2 - mn);
    unsigned long long nv =
        ((unsigned long long)__float_as_uint(s) << 32) | __float_as_uint(mn);
    old = atomicCAS(p, assumed, nv);
  } while (old != assumed);
}

// ---------------------------------------------------------------------------
// Kernel I: init global (m,s) state to (-inf, 0)
// ---------------------------------------------------------------------------
__global__ void nt_xent_init(unsigned long long* __restrict__ G) {
  G[blockIdx.x * 256 + threadIdx.x] = 0xFF800000ull;  // m=-inf, s=0
}

// ---------------------------------------------------------------------------
// Kernel T: h_i,h_j [1024][8192] fp32 -> HT [16384][1024] bf16 (transposed)
// ---------------------------------------------------------------------------
__global__ void nt_xent_transpose(const float* __restrict__ hi,
                                  const float* __restrict__ hj,
                                  unsigned short* __restrict__ HT) {
  __shared__ unsigned short tile[64][65];
  const int bn = blockIdx.x;                // n-tile: 0..255
  const int bd = blockIdx.y;                // d-tile: 0..15
  const int n0 = bn * 64, d0 = bd * 64;
  const float* src = (n0 < NC) ? hi : hj;
  const int nb = (n0 < NC) ? n0 : n0 - NC;
  const int tid = threadIdx.x;
#pragma unroll
  for (int i = 0; i < 16; ++i) {
    int idx = tid + 256 * i;
    int dl = idx >> 6, nl = idx & 63;       // coalesced read along n
    float f = src[(size_t)(d0 + dl) * NC + nb + nl];
    tile[nl][dl] = f2bf(f);
  }
  __syncthreads();
#pragma unroll
  for (int i = 0; i < 16; ++i) {
    int idx = tid + 256 * i;
    int nl = idx >> 6, dl = idx & 63;       // coalesced write along d
    HT[(size_t)(n0 + nl) * FD + d0 + dl] = tile[nl][dl];
  }
}

// ---------------------------------------------------------------------------
// Kernel G: upper-triangle 128x128-tile SYRK (m97 structure) + row/col LSE.
//   Grid: 8256 tiles (ti<=tj), XCD-chunked swizzle (8256 = 8*1032).
//   4 waves (2x2), each computes 64x64 (4x4 frags 16x16x32 bf16, K=1024).
//   LDS 32 KB: A[16 frags][1KB] + B[16 frags][1KB], frag-linear, single-buf,
//   2 barriers per k-step; 3 blocks/CU give wave-TLP to hide barrier drains.
//   Frag (kk,idx): lane l holds row/col = idx*16+(l&15), k = kk*32+(l>>4)*8.
//   C/D layout (verified): col = lane&15, row = (lane>>4)*4 + reg.
//   Epilogue: row-LSE partials (rows of ti) always; col-LSE partials
//   (rows of tj, via transpose-reduce of acc) when ti != tj. CAS-merge to G.
// ---------------------------------------------------------------------------
__global__ __launch_bounds__(256, 3)
void nt_xent_gemm_lse(const unsigned short* __restrict__ HT,
                      unsigned long long* __restrict__ G) {
  __shared__ __align__(16) unsigned char lds[32768];
  unsigned char* Abuf = lds;            // 16 KB
  unsigned char* Bbuf = lds + 16384;    // 16 KB
  float (*red)[2][64][2]  = (float (*)[2][64][2])lds;           // rows, 2 KB
  float (*redc)[2][64][2] = (float (*)[2][64][2])(lds + 4096);  // cols, 2 KB

  const int tid = threadIdx.x;
  const int w = tid >> 6, l = tid & 63;
  const int lr = l & 15;                // row/col within fragment
  const int lk = (l >> 4) * 8;          // k-offset (shorts) within 32-slice
  const int wr = w >> 1, wc = w & 1;    // wave -> 64x64 quadrant

  // ---- XCD-chunked swizzle + closed-form upper-triangle linearization ----
  const int bid = blockIdx.x;                 // 0..8255
  const int b = (bid & 7) * (NTRI / 8) + (bid >> 3);
  int ti = (int)((257.0f - sqrtf((float)(66049 - 8 * b))) * 0.5f);
  if (ti > 127) ti = 127;
  while (ti * (257 - ti) / 2 > b) --ti;                 // exact fixup
  while ((ti + 1) * (256 - ti) / 2 <= b) ++ti;
  const int tj = ti + (b - ti * (257 - ti) / 2);        // ti <= tj <= 127

  const unsigned short* Arows = HT + (((size_t)ti * BT) << 10);
  const unsigned short* Brows = HT + (((size_t)tj * BT) << 10);

  f32x4 acc[4][4];
#pragma unroll
  for (int a = 0; a < 4; ++a)
#pragma unroll
    for (int bb = 0; bb < 4; ++bb) acc[a][bb] = (f32x4){0.f, 0.f, 0.f, 0.f};

  for (int kt = 0; kt < NKT; ++kt) {
    __syncthreads();                    // prev step's frag reads complete
    const int kb = kt * 64;
    // ---- stage: 8 gload16 per wave; wave 0/1 -> A kk=0/1, wave 2/3 -> B ----
    if (w < 2) {
      const int kk = w;
#pragma unroll
      for (int q = 0; q < 8; ++q) {
        int row = q * 16 + lr;
        gld16(Arows + (((size_t)row) << 10) + kb + kk * 32 + lk,
              Abuf + (kk * 8 + q) * 1024);
      }
    } else {
      const int kk = w - 2;
#pragma unroll
      for (int q = 0; q < 8; ++q) {
        int col = q * 16 + lr;
        gld16(Brows + (((size_t)col) << 10) + kb + kk * 32 + lk,
              Bbuf + (kk * 8 + q) * 1024);
      }
    }
    __syncthreads();                    // drains vmcnt: tile ready

    // ---- frag reads (all ds_read_b128 at lane*16, conflict-free) + MFMA ----
    bf16x8 af[2][4], bf[2][4];
#pragma unroll
    for (int kk = 0; kk < 2; ++kk) {
#pragma unroll
      for (int m = 0; m < 4; ++m)
        af[kk][m] = *(const bf16x8*)(Abuf + (kk * 8 + wr * 4 + m) * 1024 + l * 16);
#pragma unroll
      for (int n = 0; n < 4; ++n)
        bf[kk][n] = *(const bf16x8*)(Bbuf + (kk * 8 + wc * 4 + n) * 1024 + l * 16);
    }
#pragma unroll
    for (int kk = 0; kk < 2; ++kk)
#pragma unroll
      for (int m = 0; m < 4; ++m)
#pragma unroll
        for (int n = 0; n < 4; ++n)
          acc[m][n] = __builtin_amdgcn_mfma_f32_16x16x32_bf16(
              af[kk][m], bf[kk][n], acc[m][n], 0, 0, 0);
  }

  __syncthreads();    // all frag reads done; safe to overlay red/redc on Abuf

  // ---- row partials: per-row (m,s) over this tile's 128 cols ----
  const int gr0 = ti * BT + wr * 64 + ((l >> 4) << 2);  // + m*16 + rg
  const int gc0 = tj * BT + wc * 64 + lr;               // + n*16
#pragma unroll
  for (int m = 0; m < 4; ++m) {
#pragma unroll
    for (int rg = 0; rg < 4; ++rg) {
      const int grow = gr0 + m * 16 + rg;
      float vs[4], mx = -INFINITY;
#pragma unroll
      for (int n = 0; n < 4; ++n) {
        float v = acc[m][n][rg] * 2.0f;           // 1/T = 2
        if (gc0 + n * 16 == grow) v = -INFINITY;  // mask true diagonal (ti==tj)
        vs[n] = v;
        mx = fmaxf(mx, v);
      }
      float sm = 0.f;
#pragma unroll
      for (int n = 0; n < 4; ++n) sm += __expf(vs[n] - mx);
      // merge across the 16 lanes (lr) sharing these rows
#pragma unroll
      for (int off = 1; off < 16; off <<= 1) {
        float m2 = __shfl_xor(mx, off, 16);
        float s2 = __shfl_xor(sm, off, 16);
        float mn = fmaxf(mx, m2);
        sm = sm * __expf(mx - mn) + s2 * __expf(m2 - mn);
        mx = mn;
      }
      if (lr == 0) {
        const int rl = m * 16 + ((l >> 4) << 2) + rg;   // row-local 0..63
        red[wr][wc][rl][0] = mx;
        red[wr][wc][rl][1] = sm;
      }
    }
  }

  // ---- col partials (ti != tj): per-col (m,s) over this tile's 128 rows ----
  if (ti != tj) {
#pragma unroll
    for (int n = 0; n < 4; ++n) {
      float v[4][4], mx = -INFINITY;
#pragma unroll
      for (int m = 0; m < 4; ++m)
#pragma unroll
        for (int rg = 0; rg < 4; ++rg) {
          float x = acc[m][n][rg] * 2.0f;         // no diagonal off-tile
          v[m][rg] = x;
          mx = fmaxf(mx, x);
        }
      float sm = 0.f;
#pragma unroll
      for (int m = 0; m < 4; ++m)
#pragma unroll
        for (int rg = 0; rg < 4; ++rg) sm += __expf(v[m][rg] - mx);
      // reduce across the 4 lane-groups (same lr = same column)
#pragma unroll
      for (int off = 16; off < 64; off <<= 1) {
        float m2 = __shfl_xor(mx, off);
        float s2 = __shfl_xor(sm, off);
        float mn = fmaxf(mx, m2);
        sm = sm * __expf(mx - mn) + s2 * __expf(m2 - mn);
        mx = mn;
      }
      if (l < 16) {
        redc[wc][wr][n * 16 + lr][0] = mx;
        redc[wc][wr][n * 16 + lr][1] = sm;
      }
    }
  }
  __syncthreads();

  // ---- combine halves, CAS-merge into global per-row state ----
  if (tid < 128) {
    const int half = tid >> 6, idx = tid & 63;
    {
      float m0 = red[half][0][idx][0], s0 = red[half][0][idx][1];
      float m1 = red[half][1][idx][0], s1 = red[half][1][idx][1];
      float mn = fmaxf(m0, m1);
      float s = s0 * __expf(m0 - mn) + s1 * __expf(m1 - mn);
      cas_merge(&G[ti * BT + half * 64 + idx], mn, s);
    }
    if (ti != tj) {
      float m0 = redc[half][0][idx][0], s0 = redc[half][0][idx][1];
      float m1 = redc[half][1][idx][0], s1 = redc[half][1][idx][1];
      float mn = fmaxf(m0, m1);
      float s = s0 * __expf(m0 - mn) + s1 * __expf(m1 - mn);
      cas_merge(&G[tj * BT + half * 64 + idx], mn, s);
    }
  }
}

// ---------------------------------------------------------------------------
// Kernel F: lse[i] = m + log(s); pos = 2*dot(HT[i],HT[partner]);
//           out += (lse - pos)/NT
// ---------------------------------------------------------------------------
__global__ void nt_xent_final(const unsigned short* __restrict__ HT,
                              const unsigned long long* __restrict__ G,
                              float* __restrict__ out) {
  const int tid = threadIdx.x;
  const int w = tid >> 6, l = tid & 63;
  const int wave = blockIdx.x * 4 + w;      // 0..1023, 16 rows each
  float local = 0.f;
  for (int rr = 0; rr < 16; ++rr) {
    int i = wave * 16 + rr;
    int p = (i + NC) & (NT - 1);
    const int4* A = (const int4*)(HT + (((size_t)i) << 10) + (l << 4));
    const int4* B = (const int4*)(HT + (((size_t)p) << 10) + (l << 4));
    union { int4 v; unsigned short u[8]; } a0, a1, b0, b1;
    a0.v = A[0]; a1.v = A[1]; b0.v = B[0]; b1.v = B[1];
    float dot = 0.f;
#pragma unroll
    for (int j = 0; j < 8; ++j) dot += bf2f(a0.u[j]) * bf2f(b0.u[j]);
#pragma unroll
    for (int j = 0; j < 8; ++j) dot += bf2f(a1.u[j]) * bf2f(b1.u[j]);
#pragma unroll
    for (int off = 1; off < 64; off <<= 1) dot += __shfl_xor(dot, off, 64);
    if (l == 0) {
      unsigned long long g = G[i];
      float m = __uint_as_float((unsigned)(g & 0xffffffffull));
      float s = __uint_as_float((unsigned)(g >> 32));
      local += m + __logf(s) - 2.0f * dot;
    }
  }
  if (l == 0) atomicAdd(out, local * (1.0f / (float)NT));
}

// ---------------------------------------------------------------------------
extern "C" void kernel_launch(void* const* d_in, const int* in_sizes, int n_in,
                              void* d_out, int out_size, void* d_ws, size_t ws_size,
                              hipStream_t stream) {
  const float* hi = (const float*)d_in[0];
  const float* hj = (const float*)d_in[1];
  unsigned short* HT = (unsigned short*)d_ws;
  unsigned long long* G = (unsigned long long*)((char*)d_ws + (size_t)NT * FD * 2);
  float* out = (float*)d_out;

  const size_t need = (size_t)NT * FD * 2 + (size_t)NT * 8;
  if (ws_size < need) return;

  hipMemsetAsync(out, 0, sizeof(float), stream);
  nt_xent_init<<<NT / 256, 256, 0, stream>>>(G);
  nt_xent_transpose<<<dim3(NT / 64, FD / 64), 256, 0, stream>>>(hi, hj, HT);
  nt_xent_gemm_lse<<<NTRI, 256, 0, stream>>>(HT, G);
  nt_xent_final<<<NT / 64, 256, 0, stream>>>(HT, G, out);
}

// Round 5
// 609.885 us; speedup vs baseline: 5.4451x; 1.2234x over previous
//
#include <hip/hip_runtime.h>
#include <stdint.h>

// Problem constants
#define FD 1024          // feature dim (K)
#define NC 8192          // classes per view
#define NT 16384         // N = 2*NC
#define BT 128           // block tile (rows == cols)
#define BK 64            // k per staged step
#define NKT (FD / BK)    // 16 k-steps
#define NTILE 128        // tile-grid dimension (16384/128)
#define NTRI 8256        // NTILE*(NTILE+1)/2 upper-triangle tiles

typedef __attribute__((ext_vector_type(8))) short bf16x8;
typedef __attribute__((ext_vector_type(4))) float f32x4;

__device__ __forceinline__ unsigned short f2bf(float f) {
  unsigned u = __float_as_uint(f);
  u += 0x7FFF + ((u >> 16) & 1);   // RNE
  return (unsigned short)(u >> 16);
}
__device__ __forceinline__ float bf2f(unsigned short s) {
  return __uint_as_float(((unsigned)s) << 16);
}

// async global->LDS, 16B/lane; LDS dest wave-uniform (HW adds lane*16)
__device__ __forceinline__ void gld16(const void* g, void* l) {
  __builtin_amdgcn_global_load_lds(
      (const __attribute__((address_space(1))) unsigned int*)g,
      (__attribute__((address_space(3))) unsigned int*)l, 16, 0, 0);
}

// online-LSE merge of (m2,s2) into packed global state {lo: m bits, hi: s bits}
__device__ __forceinline__ void cas_merge(unsigned long long* p, float m2, float s2) {
  unsigned long long old = *p, assumed;
  do {
    assumed = old;
    float m1 = __uint_as_float((unsigned)(assumed & 0xffffffffull));
    float s1 = __uint_as_float((unsigned)(assumed >> 32));
    float mn = fmaxf(m1, m2);                       // m2 always finite
    float s = s1 * __expf(m1 - mn) + s2 * __expf(m2 - mn);
    unsigned long long nv =
        ((unsigned long long)__float_as_uint(s) << 32) | __float_as_uint(mn);
    old = atomicCAS(p, assumed, nv);
  } while (old != assumed);
}

// ---------------------------------------------------------------------------
// Kernel I: init global (m,s) state to (-inf, 0)
// ---------------------------------------------------------------------------
__global__ void nt_xent_init(unsigned long long* __restrict__ G) {
  G[blockIdx.x * 256 + threadIdx.x] = 0xFF800000ull;  // m=-inf, s=0
}

// ---------------------------------------------------------------------------
// Kernel T: h_i,h_j [1024][8192] fp32 -> HT [16384][1024] bf16 (transposed)
// ---------------------------------------------------------------------------
__global__ void nt_xent_transpose(const float* __restrict__ hi,
                                  const float* __restrict__ hj,
                                  unsigned short* __restrict__ HT) {
  __shared__ unsigned short tile[64][65];
  const int bn = blockIdx.x;                // n-tile: 0..255
  const int bd = blockIdx.y;                // d-tile: 0..15
  const int n0 = bn * 64, d0 = bd * 64;
  const float* src = (n0 < NC) ? hi : hj;
  const int nb = (n0 < NC) ? n0 : n0 - NC;
  const int tid = threadIdx.x;
#pragma unroll
  for (int i = 0; i < 16; ++i) {
    int idx = tid + 256 * i;
    int dl = idx >> 6, nl = idx & 63;       // coalesced read along n
    float f = src[(size_t)(d0 + dl) * NC + nb + nl];
    tile[nl][dl] = f2bf(f);
  }
  __syncthreads();
#pragma unroll
  for (int i = 0; i < 16; ++i) {
    int idx = tid + 256 * i;
    int nl = idx >> 6, dl = idx & 63;       // coalesced write along d
    HT[(size_t)(n0 + nl) * FD + d0 + dl] = tile[nl][dl];
  }
}

// ---------------------------------------------------------------------------
// Kernel G: upper-triangle 128x128-tile SYRK + row/col LSE.
//   SUPERTILED triangle walk for L2 locality:
//     super-grid 16x16 of 8x8-tile supertiles (8 A + 8 B panels = 4 MB = L2).
//     16 diag supertiles (36 pairs) + 120 off-diag (64 pairs) = 8256 blocks.
//     Per XCD: exactly 2 diag + 15 off-diag = 1032 blocks (bijective).
//     XCD x's off-diag supertiles share SI rows -> A panels persist in L2.
//   4 waves (2x2), each 64x64 (4x4 frags 16x16x32 bf16, K=1024); LDS 32 KB
//   frag-linear single-buffered, 2 barriers/k-step, 4 blocks/CU for TLP.
//   Frag (kk,idx): lane l holds row/col = idx*16+(l&15), k = kk*32+(l>>4)*8.
//   C/D layout (verified): col = lane&15, row = (lane>>4)*4 + reg.
//   Epilogue: row-LSE partials always; col-LSE partials when ti != tj.
// ---------------------------------------------------------------------------
__global__ __launch_bounds__(256, 4)
void nt_xent_gemm_lse(const unsigned short* __restrict__ HT,
                      unsigned long long* __restrict__ G) {
  __shared__ __align__(16) unsigned char lds[32768];
  unsigned char* Abuf = lds;            // 16 KB
  unsigned char* Bbuf = lds + 16384;    // 16 KB
  float (*red)[2][64][2]  = (float (*)[2][64][2])lds;           // rows, 2 KB
  float (*redc)[2][64][2] = (float (*)[2][64][2])(lds + 4096);  // cols, 2 KB

  const int tid = threadIdx.x;
  const int w = tid >> 6, l = tid & 63;
  const int lr = l & 15;                // row/col within fragment
  const int lk = (l >> 4) * 8;          // k-offset (shorts) within 32-slice
  const int wr = w >> 1, wc = w & 1;    // wave -> 64x64 quadrant

  // ---- supertiled bijective triangle mapping (uniform per block) ----
  int ti, tj;
  {
    const int xcd = blockIdx.x & 7, p = blockIdx.x >> 3;   // p: 0..1031
    if (p < 72) {
      // two diagonal supertiles per XCD: d = 2*xcd + {0,1}
      const int hi = (p >= 36) ? 1 : 0;
      const int d = 2 * xcd + hi;
      const int q = p - hi * 36;                 // 0..35 within 8x8 triangle
      int i = 0;
      while ((i + 1) * 8 - ((i + 1) * i) / 2 <= q) ++i;
      const int j = i + (q - (i * 8 - (i * (i - 1)) / 2));
      ti = d * 8 + i; tj = d * 8 + j;
    } else {
      // 15 off-diagonal supertiles per XCD, mostly sharing SI (A-panel reuse)
      const int t = p - 72;
      const int o = 15 * xcd + (t >> 6);         // 0..119 strict-upper index
      const int q = t & 63;
      int SI = 0;
      while (15 * (SI + 1) - ((SI + 1) * SI) / 2 <= o) ++SI;
      const int SJ = SI + 1 + (o - (15 * SI - (SI * (SI - 1)) / 2));
      ti = SI * 8 + (q >> 3); tj = SJ * 8 + (q & 7);
    }
  }

  const unsigned short* Arows = HT + (((size_t)ti * BT) << 10);
  const unsigned short* Brows = HT + (((size_t)tj * BT) << 10);

  f32x4 acc[4][4];
#pragma unroll
  for (int a = 0; a < 4; ++a)
#pragma unroll
    for (int bb = 0; bb < 4; ++bb) acc[a][bb] = (f32x4){0.f, 0.f, 0.f, 0.f};

  for (int kt = 0; kt < NKT; ++kt) {
    __syncthreads();                    // prev step's frag reads complete
    const int kb = kt * 64;
    // ---- stage: 8 gload16 per wave; wave 0/1 -> A kk=0/1, wave 2/3 -> B ----
    if (w < 2) {
      const int kk = w;
#pragma unroll
      for (int q = 0; q < 8; ++q) {
        int row = q * 16 + lr;
        gld16(Arows + (((size_t)row) << 10) + kb + kk * 32 + lk,
              Abuf + (kk * 8 + q) * 1024);
      }
    } else {
      const int kk = w - 2;
#pragma unroll
      for (int q = 0; q < 8; ++q) {
        int col = q * 16 + lr;
        gld16(Brows + (((size_t)col) << 10) + kb + kk * 32 + lk,
              Bbuf + (kk * 8 + q) * 1024);
      }
    }
    __syncthreads();                    // drains vmcnt: tile ready

    // ---- frag reads (all ds_read_b128 at lane*16, conflict-free) + MFMA ----
    bf16x8 af[2][4], bf[2][4];
#pragma unroll
    for (int kk = 0; kk < 2; ++kk) {
#pragma unroll
      for (int m = 0; m < 4; ++m)
        af[kk][m] = *(const bf16x8*)(Abuf + (kk * 8 + wr * 4 + m) * 1024 + l * 16);
#pragma unroll
      for (int n = 0; n < 4; ++n)
        bf[kk][n] = *(const bf16x8*)(Bbuf + (kk * 8 + wc * 4 + n) * 1024 + l * 16);
    }
#pragma unroll
    for (int kk = 0; kk < 2; ++kk)
#pragma unroll
      for (int m = 0; m < 4; ++m)
#pragma unroll
        for (int n = 0; n < 4; ++n)
          acc[m][n] = __builtin_amdgcn_mfma_f32_16x16x32_bf16(
              af[kk][m], bf[kk][n], acc[m][n], 0, 0, 0);
  }

  __syncthreads();    // all frag reads done; safe to overlay red/redc on Abuf

  // ---- row partials: per-row (m,s) over this tile's 128 cols ----
  const int gr0 = ti * BT + wr * 64 + ((l >> 4) << 2);  // + m*16 + rg
  const int gc0 = tj * BT + wc * 64 + lr;               // + n*16
#pragma unroll
  for (int m = 0; m < 4; ++m) {
#pragma unroll
    for (int rg = 0; rg < 4; ++rg) {
      const int grow = gr0 + m * 16 + rg;
      float vs[4], mx = -INFINITY;
#pragma unroll
      for (int n = 0; n < 4; ++n) {
        float v = acc[m][n][rg] * 2.0f;           // 1/T = 2
        if (gc0 + n * 16 == grow) v = -INFINITY;  // mask true diagonal (ti==tj)
        vs[n] = v;
        mx = fmaxf(mx, v);
      }
      float sm = 0.f;
#pragma unroll
      for (int n = 0; n < 4; ++n) sm += __expf(vs[n] - mx);
      // merge across the 16 lanes (lr) sharing these rows
#pragma unroll
      for (int off = 1; off < 16; off <<= 1) {
        float m2 = __shfl_xor(mx, off, 16);
        float s2 = __shfl_xor(sm, off, 16);
        float mn = fmaxf(mx, m2);
        sm = sm * __expf(mx - mn) + s2 * __expf(m2 - mn);
        mx = mn;
      }
      if (lr == 0) {
        const int rl = m * 16 + ((l >> 4) << 2) + rg;   // row-local 0..63
        red[wr][wc][rl][0] = mx;
        red[wr][wc][rl][1] = sm;
      }
    }
  }

  // ---- col partials (ti != tj): per-col (m,s) over this tile's 128 rows ----
  if (ti != tj) {
#pragma unroll
    for (int n = 0; n < 4; ++n) {
      float v[4][4], mx = -INFINITY;
#pragma unroll
      for (int m = 0; m < 4; ++m)
#pragma unroll
        for (int rg = 0; rg < 4; ++rg) {
          float x = acc[m][n][rg] * 2.0f;         // no diagonal off-tile
          v[m][rg] = x;
          mx = fmaxf(mx, x);
        }
      float sm = 0.f;
#pragma unroll
      for (int m = 0; m < 4; ++m)
#pragma unroll
        for (int rg = 0; rg < 4; ++rg) sm += __expf(v[m][rg] - mx);
      // reduce across the 4 lane-groups (same lr = same column)
#pragma unroll
      for (int off = 16; off < 64; off <<= 1) {
        float m2 = __shfl_xor(mx, off);
        float s2 = __shfl_xor(sm, off);
        float mn = fmaxf(mx, m2);
        sm = sm * __expf(mx - mn) + s2 * __expf(m2 - mn);
        mx = mn;
      }
      if (l < 16) {
        redc[wc][wr][n * 16 + lr][0] = mx;
        redc[wc][wr][n * 16 + lr][1] = sm;
      }
    }
  }
  __syncthreads();

  // ---- combine halves, CAS-merge into global per-row state ----
  if (tid < 128) {
    const int half = tid >> 6, idx = tid & 63;
    {
      float m0 = red[half][0][idx][0], s0 = red[half][0][idx][1];
      float m1 = red[half][1][idx][0], s1 = red[half][1][idx][1];
      float mn = fmaxf(m0, m1);
      float s = s0 * __expf(m0 - mn) + s1 * __expf(m1 - mn);
      cas_merge(&G[ti * BT + half * 64 + idx], mn, s);
    }
    if (ti != tj) {
      float m0 = redc[half][0][idx][0], s0 = redc[half][0][idx][1];
      float m1 = redc[half][1][idx][0], s1 = redc[half][1][idx][1];
      float mn = fmaxf(m0, m1);
      float s = s0 * __expf(m0 - mn) + s1 * __expf(m1 - mn);
      cas_merge(&G[tj * BT + half * 64 + idx], mn, s);
    }
  }
}

// ---------------------------------------------------------------------------
// Kernel F: lse[i] = m + log(s); pos = 2*dot(HT[i],HT[partner]);
//           out += (lse - pos)/NT
// ---------------------------------------------------------------------------
__global__ void nt_xent_final(const unsigned short* __restrict__ HT,
                              const unsigned long long* __restrict__ G,
                              float* __restrict__ out) {
  const int tid = threadIdx.x;
  const int w = tid >> 6, l = tid & 63;
  const int wave = blockIdx.x * 4 + w;      // 0..1023, 16 rows each
  float local = 0.f;
  for (int rr = 0; rr < 16; ++rr) {
    int i = wave * 16 + rr;
    int p = (i + NC) & (NT - 1);
    const int4* A = (const int4*)(HT + (((size_t)i) << 10) + (l << 4));
    const int4* B = (const int4*)(HT + (((size_t)p) << 10) + (l << 4));
    union { int4 v; unsigned short u[8]; } a0, a1, b0, b1;
    a0.v = A[0]; a1.v = A[1]; b0.v = B[0]; b1.v = B[1];
    float dot = 0.f;
#pragma unroll
    for (int j = 0; j < 8; ++j) dot += bf2f(a0.u[j]) * bf2f(b0.u[j]);
#pragma unroll
    for (int j = 0; j < 8; ++j) dot += bf2f(a1.u[j]) * bf2f(b1.u[j]);
#pragma unroll
    for (int off = 1; off < 64; off <<= 1) dot += __shfl_xor(dot, off, 64);
    if (l == 0) {
      unsigned long long g = G[i];
      float m = __uint_as_float((unsigned)(g & 0xffffffffull));
      float s = __uint_as_float((unsigned)(g >> 32));
      local += m + __logf(s) - 2.0f * dot;
    }
  }
  if (l == 0) atomicAdd(out, local * (1.0f / (float)NT));
}

// ---------------------------------------------------------------------------
extern "C" void kernel_launch(void* const* d_in, const int* in_sizes, int n_in,
                              void* d_out, int out_size, void* d_ws, size_t ws_size,
                              hipStream_t stream) {
  const float* hi = (const float*)d_in[0];
  const float* hj = (const float*)d_in[1];
  unsigned short* HT = (unsigned short*)d_ws;
  unsigned long long* G = (unsigned long long*)((char*)d_ws + (size_t)NT * FD * 2);
  float* out = (float*)d_out;

  const size_t need = (size_t)NT * FD * 2 + (size_t)NT * 8;
  if (ws_size < need) return;

  hipMemsetAsync(out, 0, sizeof(float), stream);
  nt_xent_init<<<NT / 256, 256, 0, stream>>>(G);
  nt_xent_transpose<<<dim3(NT / 64, FD / 64), 256, 0, stream>>>(hi, hj, HT);
  nt_xent_gemm_lse<<<NTRI, 256, 0, stream>>>(HT, G);
  nt_xent_final<<<NT / 64, 256, 0, stream>>>(HT, G, out);
}

// Round 6
// 546.988 us; speedup vs baseline: 6.0712x; 1.1150x over previous
//
#include <hip/hip_runtime.h>
#include <stdint.h>

// Problem constants
#define FD 1024          // feature dim (K)
#define NC 8192          // classes per view
#define NT 16384         // N = 2*NC
#define NKT 16           // K-tiles of 64
#define NTILE2 64        // 256-tile grid dimension
#define NTRI2 2080       // 64*65/2 upper-triangle tiles

typedef __attribute__((ext_vector_type(8))) short bf16x8;
typedef __attribute__((ext_vector_type(4))) float f32x4;

__device__ __forceinline__ unsigned short f2bf(float f) {
  unsigned u = __float_as_uint(f);
  u += 0x7FFF + ((u >> 16) & 1);   // RNE
  return (unsigned short)(u >> 16);
}
__device__ __forceinline__ float bf2f(unsigned short s) {
  return __uint_as_float(((unsigned)s) << 16);
}

// async global->LDS, 16B/lane; LDS dest wave-uniform (HW adds lane*16)
__device__ __forceinline__ void gld16(const void* g, void* l) {
  __builtin_amdgcn_global_load_lds(
      (const __attribute__((address_space(1))) unsigned int*)g,
      (__attribute__((address_space(3))) unsigned int*)l, 16, 0, 0);
}

// online-LSE merge of (m2,s2) into packed global state {lo: m bits, hi: s bits}
__device__ __forceinline__ void cas_merge(unsigned long long* p, float m2, float s2) {
  unsigned long long old = *p, assumed;
  do {
    assumed = old;
    float m1 = __uint_as_float((unsigned)(assumed & 0xffffffffull));
    float s1 = __uint_as_float((unsigned)(assumed >> 32));
    float mn = fmaxf(m1, m2);                       // m2 always finite
    float s = s1 * __expf(m1 - mn) + s2 * __expf(m2 - mn);
    unsigned long long nv =
        ((unsigned long long)__float_as_uint(s) << 32) | __float_as_uint(mn);
    old = atomicCAS(p, assumed, nv);
  } while (old != assumed);
}

// ---------------------------------------------------------------------------
__global__ void nt_xent_init(unsigned long long* __restrict__ G) {
  G[blockIdx.x * 256 + threadIdx.x] = 0xFF800000ull;  // m=-inf, s=0
}

// ---------------------------------------------------------------------------
// Kernel T: h_i,h_j [1024][8192] fp32 -> HT [16384][1024] bf16 (transposed)
// ---------------------------------------------------------------------------
__global__ void nt_xent_transpose(const float* __restrict__ hi,
                                  const float* __restrict__ hj,
                                  unsigned short* __restrict__ HT) {
  __shared__ unsigned short tile[64][65];
  const int bn = blockIdx.x, bd = blockIdx.y;
  const int n0 = bn * 64, d0 = bd * 64;
  const float* src = (n0 < NC) ? hi : hj;
  const int nb = (n0 < NC) ? n0 : n0 - NC;
  const int tid = threadIdx.x;
#pragma unroll
  for (int i = 0; i < 16; ++i) {
    int idx = tid + 256 * i;
    int dl = idx >> 6, nl = idx & 63;
    float f = src[(size_t)(d0 + dl) * NC + nb + nl];
    tile[nl][dl] = f2bf(f);
  }
  __syncthreads();
#pragma unroll
  for (int i = 0; i < 16; ++i) {
    int idx = tid + 256 * i;
    int nl = idx >> 6, dl = idx & 63;
    HT[(size_t)(n0 + nl) * FD + d0 + dl] = tile[nl][dl];
  }
}

// ---------------------------------------------------------------------------
// Kernel G: 256x256-tile symmetric SYRK, 8-phase deep-pipelined schedule
//   (T3+T4 counted vmcnt + T5 setprio), + row/col LSE partials -> CAS merge.
//
//   Grid: 2080 upper-triangle tiles on a 64x64 grid, supertiled 4x4
//   (4 A + 4 B panels of 512 KB = 4 MB = one XCD L2), bijective per-XCD
//   chunking: 2080 = 8 * (2 diag supertiles (10) + 15 off-diag (16)).
//
//   512 thr = 8 waves (wr=w>>2 in {0,1}: 128-row half; wc=w&3: 64-col strip).
//   acc[8][4] f32x4 (128 VGPR). MFMA 16x16x32 bf16.
//   LDS 128 KiB: buf{0,1} x (A 32K | B 32K), frag-linear: frag f = kk*16+mi
//   is a 1 KiB slot; lane l holds row mi*16+(l&15), k = kk*32+(l>>4)*8.
//
//   Per K-tile T (buffer T&1), 4 phases:
//     P1: read B kk0 (4) + A kk0 m0..3 (4); stage grp (A kk1 of T+1)
//     P2: read A kk0 m4..7;                 stage grp (B kk1 of T+1); vmcnt(8)
//     P3: read B kk1 + A kk1 m0..3;         stage grp (A kk0 of T+2)
//     P4: read A kk1 m4..7;                 stage grp (B kk0 of T+2); vmcnt(8)
//   each phase: [reads; stage; (vmcnt)] barrier; lgkmcnt(0); setprio(1);
//   16 MFMA; setprio(0); barrier.  Each staged group lands exactly one phase
//   after its region's last reader (barrier-separated => race-free); consumers
//   run >=6 phases after issue, guaranteed by the counted vmcnt(8) waits.
//   Tail uniform: stage targets wrap mod 16 (dead-region writes, harmless).
// ---------------------------------------------------------------------------
__global__ __launch_bounds__(512, 2)
void nt_xent_gemm_lse(const unsigned short* __restrict__ HT,
                      unsigned long long* __restrict__ G) {
  __shared__ __align__(16) unsigned char lds[131072];

  const int tid = threadIdx.x;
  const int w = tid >> 6, l = tid & 63;
  const int lr = l & 15;
  const int lk = (l >> 4) * 8;
  const int wr = w >> 2, wc = w & 3;

  // ---- supertiled bijective triangle mapping ----
  int ti, tj;
  {
    const int xcd = blockIdx.x & 7, p = blockIdx.x >> 3;   // p: 0..259
    if (p < 20) {
      const int hi = (p >= 10) ? 1 : 0;
      const int d = 2 * xcd + hi;
      const int q = p - hi * 10;                 // 0..9 in 4x4 triangle
      int i = 0;
      while ((i + 1) * 4 - ((i + 1) * i) / 2 <= q) ++i;
      const int j = i + (q - (i * 4 - (i * (i - 1)) / 2));
      ti = d * 4 + i; tj = d * 4 + j;
    } else {
      const int t = p - 20;                      // 0..239
      const int o = 15 * xcd + (t >> 4);         // 0..119 strict-upper index
      const int q = t & 15;
      int SI = 0;
      while (15 * (SI + 1) - ((SI + 1) * SI) / 2 <= o) ++SI;
      const int SJ = SI + 1 + (o - (15 * SI - (SI * (SI - 1)) / 2));
      ti = SI * 4 + (q >> 2); tj = SJ * 4 + (q & 3);
    }
  }

  const unsigned short* Abase = HT + (((size_t)ti) << 18);   // ti*256*1024
  const unsigned short* Bbase = HT + (((size_t)tj) << 18);

// stage one group (16 frags, 2 per wave) of K-tile TT: GRP 0=Akk0 1=Bkk0 2=Akk1 3=Bkk1
#define STAGE(TT, GRP) do {                                                  \
    const int _t = (TT), _g = (GRP);                                         \
    const int _buf = _t & 1, _kk = (_g >> 1) & 1, _isB = _g & 1;             \
    const unsigned short* _src = _isB ? Bbase : Abase;                       \
    unsigned char* _dst = lds + _buf * 65536 + _isB * 32768 + _kk * 16384;   \
    const int _ko = (_t & 15) * 64 + _kk * 32 + lk;                          \
    const int _mi0 = 2 * w;                                                  \
    gld16(_src + (((size_t)(_mi0 * 16 + lr)) << 10) + _ko,                   \
          _dst + _mi0 * 1024);                                               \
    gld16(_src + (((size_t)((_mi0 + 1) * 16 + lr)) << 10) + _ko,             \
          _dst + (_mi0 + 1) * 1024);                                         \
  } while (0)

#define RDA(BUF, KK, MI) \
  (*(const bf16x8*)(lds + (BUF) * 65536 + (KK) * 16384 + (wr * 8 + (MI)) * 1024 + l * 16))
#define RDB(BUF, KK, N) \
  (*(const bf16x8*)(lds + (BUF) * 65536 + 32768 + (KK) * 16384 + (wc * 4 + (N)) * 1024 + l * 16))

#define MFMA16(MB)                                                           \
  _Pragma("unroll") for (int m = 0; m < 4; ++m)                              \
  _Pragma("unroll") for (int n = 0; n < 4; ++n)                              \
    acc[(MB) + m][n] = __builtin_amdgcn_mfma_f32_16x16x32_bf16(              \
        av[m], bv[n], acc[(MB) + m][n], 0, 0, 0);

  f32x4 acc[8][4];
#pragma unroll
  for (int a = 0; a < 8; ++a)
#pragma unroll
    for (int b = 0; b < 4; ++b) acc[a][b] = (f32x4){0.f, 0.f, 0.f, 0.f};

  // ---- prologue: stage K-tiles 0,1 fully; ensure K0 landed ----
#pragma unroll
  for (int t0 = 0; t0 < 2; ++t0)
#pragma unroll
    for (int g0 = 0; g0 < 4; ++g0) STAGE(t0, g0);
  asm volatile("s_waitcnt vmcnt(8)" ::: "memory");
  __builtin_amdgcn_s_barrier();

#pragma unroll 2
  for (int T = 0; T < NKT; ++T) {
    const int buf = T & 1;
    bf16x8 av[4], bv[4];

    // ---------------- P1: kk=0, m 0..3 ----------------
    bv[0] = RDB(buf, 0, 0); bv[1] = RDB(buf, 0, 1);
    bv[2] = RDB(buf, 0, 2); bv[3] = RDB(buf, 0, 3);
    av[0] = RDA(buf, 0, 0); av[1] = RDA(buf, 0, 1);
    av[2] = RDA(buf, 0, 2); av[3] = RDA(buf, 0, 3);
    if (T > 0) STAGE(T + 1, 2);                 // A kk1 of T+1
    __builtin_amdgcn_s_barrier();
    asm volatile("s_waitcnt lgkmcnt(0)" ::: "memory");
    __builtin_amdgcn_s_setprio(1);
    MFMA16(0)
    __builtin_amdgcn_s_setprio(0);
    __builtin_amdgcn_s_barrier();

    // ---------------- P2: kk=0, m 4..7 ----------------
    av[0] = RDA(buf, 0, 4); av[1] = RDA(buf, 0, 5);
    av[2] = RDA(buf, 0, 6); av[3] = RDA(buf, 0, 7);
    if (T > 0) STAGE(T + 1, 3);                 // B kk1 of T+1
    asm volatile("s_waitcnt vmcnt(8)" ::: "memory");
    __builtin_amdgcn_s_barrier();
    asm volatile("s_waitcnt lgkmcnt(0)" ::: "memory");
    __builtin_amdgcn_s_setprio(1);
    MFMA16(4)
    __builtin_amdgcn_s_setprio(0);
    __builtin_amdgcn_s_barrier();

    // ---------------- P3: kk=1, m 0..3 ----------------
    bv[0] = RDB(buf, 1, 0); bv[1] = RDB(buf, 1, 1);
    bv[2] = RDB(buf, 1, 2); bv[3] = RDB(buf, 1, 3);
    av[0] = RDA(buf, 1, 0); av[1] = RDA(buf, 1, 1);
    av[2] = RDA(buf, 1, 2); av[3] = RDA(buf, 1, 3);
    STAGE(T + 2, 0);                            // A kk0 of T+2 (wraps in tail)
    __builtin_amdgcn_s_barrier();
    asm volatile("s_waitcnt lgkmcnt(0)" ::: "memory");
    __builtin_amdgcn_s_setprio(1);
    MFMA16(0)
    __builtin_amdgcn_s_setprio(0);
    __builtin_amdgcn_s_barrier();

    // ---------------- P4: kk=1, m 4..7 ----------------
    av[0] = RDA(buf, 1, 4); av[1] = RDA(buf, 1, 5);
    av[2] = RDA(buf, 1, 6); av[3] = RDA(buf, 1, 7);
    STAGE(T + 2, 1);                            // B kk0 of T+2 (wraps in tail)
    asm volatile("s_waitcnt vmcnt(8)" ::: "memory");
    __builtin_amdgcn_s_barrier();
    asm volatile("s_waitcnt lgkmcnt(0)" ::: "memory");
    __builtin_amdgcn_s_setprio(1);
    MFMA16(4)
    __builtin_amdgcn_s_setprio(0);
    __builtin_amdgcn_s_barrier();
  }

  // drain all in-flight stages before reusing LDS
  asm volatile("s_waitcnt vmcnt(0)" ::: "memory");
  __builtin_amdgcn_s_barrier();

  // ---- epilogue: LSE partials ----
  float (*red)[4][128][2] = (float (*)[4][128][2])lds;           // [wr][wc][rl] 8 KB
  float (*redc)[2][64][2] = (float (*)[2][64][2])(lds + 8192);   // [wc][wr][cl] 4 KB

  const int gr0 = ti * 256 + wr * 128 + ((l >> 4) << 2);  // + m*16 + rg
  const int gc0 = tj * 256 + wc * 64 + lr;                // + n*16

  // row partials: per-row (m,s) over this tile's 256 cols (wave: 64 cols)
#pragma unroll
  for (int m = 0; m < 8; ++m) {
#pragma unroll
    for (int rg = 0; rg < 4; ++rg) {
      const int grow = gr0 + m * 16 + rg;
      float vs[4];
      float mx = -INFINITY;
#pragma unroll
      for (int n = 0; n < 4; ++n) {
        float v = acc[m][n][rg] * 2.0f;            // 1/T = 2
        if (gc0 + n * 16 == grow) v = -INFINITY;   // mask diagonal (ti==tj)
        vs[n] = v;
        mx = fmaxf(mx, v);
      }
#pragma unroll
      for (int off = 1; off < 16; off <<= 1) mx = fmaxf(mx, __shfl_xor(mx, off, 16));
      float sm = 0.f;
#pragma unroll
      for (int n = 0; n < 4; ++n) sm += __expf(vs[n] - mx);
#pragma unroll
      for (int off = 1; off < 16; off <<= 1) sm += __shfl_xor(sm, off, 16);
      if (lr == 0) {
        const int rl = m * 16 + ((l >> 4) << 2) + rg;   // 0..127
        red[wr][wc][rl][0] = mx;
        red[wr][wc][rl][1] = sm;
      }
    }
  }

  // col partials (ti != tj): per-col (m,s) over this tile's 256 rows
  if (ti != tj) {
#pragma unroll
    for (int n = 0; n < 4; ++n) {
      float mx = -INFINITY;
#pragma unroll
      for (int m = 0; m < 8; ++m)
#pragma unroll
        for (int rg = 0; rg < 4; ++rg) mx = fmaxf(mx, acc[m][n][rg] * 2.0f);
      mx = fmaxf(mx, __shfl_xor(mx, 16));
      mx = fmaxf(mx, __shfl_xor(mx, 32));
      float sm = 0.f;
#pragma unroll
      for (int m = 0; m < 8; ++m)
#pragma unroll
        for (int rg = 0; rg < 4; ++rg) sm += __expf(acc[m][n][rg] * 2.0f - mx);
      sm += __shfl_xor(sm, 16);
      sm += __shfl_xor(sm, 32);
      if (l < 16) {
        redc[wc][wr][n * 16 + lr][0] = mx;
        redc[wc][wr][n * 16 + lr][1] = sm;
      }
    }
  }
  __syncthreads();

  // ---- merge + CAS into global per-row state ----
  if (tid < 256) {
    const int row = tid, wrr = row >> 7, rl = row & 127;
    float M = -INFINITY;
#pragma unroll
    for (int c = 0; c < 4; ++c) M = fmaxf(M, red[wrr][c][rl][0]);
    float S = 0.f;
#pragma unroll
    for (int c = 0; c < 4; ++c) S += red[wrr][c][rl][1] * __expf(red[wrr][c][rl][0] - M);
    cas_merge(&G[ti * 256 + row], M, S);
  } else if (ti != tj) {
    const int col = tid - 256, wcc = col >> 6, cl = col & 63;
    float m0 = redc[wcc][0][cl][0], s0 = redc[wcc][0][cl][1];
    float m1 = redc[wcc][1][cl][0], s1 = redc[wcc][1][cl][1];
    float mn = fmaxf(m0, m1);
    float s = s0 * __expf(m0 - mn) + s1 * __expf(m1 - mn);
    cas_merge(&G[tj * 256 + col], mn, s);
  }

#undef STAGE
#undef RDA
#undef RDB
#undef MFMA16
}

// ---------------------------------------------------------------------------
// Kernel F: lse[i] = m + log(s); pos = 2*dot(HT[i],HT[partner]);
//           out += (lse - pos)/NT
// ---------------------------------------------------------------------------
__global__ void nt_xent_final(const unsigned short* __restrict__ HT,
                              const unsigned long long* __restrict__ G,
                              float* __restrict__ out) {
  const int tid = threadIdx.x;
  const int w = tid >> 6, l = tid & 63;
  const int wave = blockIdx.x * 4 + w;      // 0..1023, 16 rows each
  float local = 0.f;
  for (int rr = 0; rr < 16; ++rr) {
    int i = wave * 16 + rr;
    int p = (i + NC) & (NT - 1);
    const int4* A = (const int4*)(HT + (((size_t)i) << 10) + (l << 4));
    const int4* B = (const int4*)(HT + (((size_t)p) << 10) + (l << 4));
    union { int4 v; unsigned short u[8]; } a0, a1, b0, b1;
    a0.v = A[0]; a1.v = A[1]; b0.v = B[0]; b1.v = B[1];
    float dot = 0.f;
#pragma unroll
    for (int j = 0; j < 8; ++j) dot += bf2f(a0.u[j]) * bf2f(b0.u[j]);
#pragma unroll
    for (int j = 0; j < 8; ++j) dot += bf2f(a1.u[j]) * bf2f(b1.u[j]);
#pragma unroll
    for (int off = 1; off < 64; off <<= 1) dot += __shfl_xor(dot, off, 64);
    if (l == 0) {
      unsigned long long g = G[i];
      float m = __uint_as_float((unsigned)(g & 0xffffffffull));
      float s = __uint_as_float((unsigned)(g >> 32));
      local += m + __logf(s) - 2.0f * dot;
    }
  }
  if (l == 0) atomicAdd(out, local * (1.0f / (float)NT));
}

// ---------------------------------------------------------------------------
extern "C" void kernel_launch(void* const* d_in, const int* in_sizes, int n_in,
                              void* d_out, int out_size, void* d_ws, size_t ws_size,
                              hipStream_t stream) {
  const float* hi = (const float*)d_in[0];
  const float* hj = (const float*)d_in[1];
  unsigned short* HT = (unsigned short*)d_ws;
  unsigned long long* G = (unsigned long long*)((char*)d_ws + (size_t)NT * FD * 2);
  float* out = (float*)d_out;

  const size_t need = (size_t)NT * FD * 2 + (size_t)NT * 8;
  if (ws_size < need) return;

  hipMemsetAsync(out, 0, sizeof(float), stream);
  nt_xent_init<<<NT / 256, 256, 0, stream>>>(G);
  nt_xent_transpose<<<dim3(NT / 64, FD / 64), 256, 0, stream>>>(hi, hj, HT);
  nt_xent_gemm_lse<<<NTRI2, 512, 0, stream>>>(HT, G);
  nt_xent_final<<<NT / 64, 256, 0, stream>>>(HT, G, out);
}

// Round 7
// 524.009 us; speedup vs baseline: 6.3374x; 1.0439x over previous
//
#include <hip/hip_runtime.h>
#include <stdint.h>

// Problem constants
#define FD 1024          // feature dim (K)
#define NC 8192          // classes per view
#define NT 16384         // N = 2*NC
#define NKT 16           // K-tiles of 64
#define NTRI2 2080       // 64*65/2 upper-triangle 256x256 tiles

typedef __attribute__((ext_vector_type(8))) short bf16x8;
typedef __attribute__((ext_vector_type(4))) float f32x4;

__device__ __forceinline__ unsigned short f2bf(float f) {
  unsigned u = __float_as_uint(f);
  u += 0x7FFF + ((u >> 16) & 1);   // RNE
  return (unsigned short)(u >> 16);
}
__device__ __forceinline__ float bf2f(unsigned short s) {
  return __uint_as_float(((unsigned)s) << 16);
}

// async global->LDS, 16B/lane; LDS dest wave-uniform (HW adds lane*16)
__device__ __forceinline__ void gld16(const void* g, void* l) {
  __builtin_amdgcn_global_load_lds(
      (const __attribute__((address_space(1))) unsigned int*)g,
      (__attribute__((address_space(3))) unsigned int*)l, 16, 0, 0);
}

// online-LSE merge of (m2,s2) into packed global state {lo: m bits, hi: s bits}
__device__ __forceinline__ void cas_merge(unsigned long long* p, float m2, float s2) {
  unsigned long long old = *p, assumed;
  do {
    assumed = old;
    float m1 = __uint_as_float((unsigned)(assumed & 0xffffffffull));
    float s1 = __uint_as_float((unsigned)(assumed >> 32));
    float mn = fmaxf(m1, m2);                       // m2 always finite
    float s = s1 * __expf(m1 - mn) + s2 * __expf(m2 - mn);
    unsigned long long nv =
        ((unsigned long long)__float_as_uint(s) << 32) | __float_as_uint(mn);
    old = atomicCAS(p, assumed, nv);
  } while (old != assumed);
}

// per-XCD supertiled triangle decode (4x4-tile supertiles on 16x16 supergrid)
__device__ __forceinline__ void decode_tile(int xcd, int p, int& ti, int& tj) {
  if (p < 20) {
    const int hi = (p >= 10) ? 1 : 0;
    const int d = 2 * xcd + hi;
    const int q = p - hi * 10;                 // 0..9 in 4x4 triangle
    int i = 0;
    while ((i + 1) * 4 - ((i + 1) * i) / 2 <= q) ++i;
    const int j = i + (q - (i * 4 - (i * (i - 1)) / 2));
    ti = d * 4 + i; tj = d * 4 + j;
  } else {
    const int t = p - 20;                      // 0..239
    const int o = 15 * xcd + (t >> 4);         // 0..119 strict-upper index
    const int q = t & 15;
    int SI = 0;
    while (15 * (SI + 1) - ((SI + 1) * SI) / 2 <= o) ++SI;
    const int SJ = SI + 1 + (o - (15 * SI - (SI * (SI - 1)) / 2));
    ti = SI * 4 + (q >> 2); tj = SJ * 4 + (q & 3);
  }
}

// ---------------------------------------------------------------------------
__global__ void nt_xent_init(unsigned long long* __restrict__ G) {
  G[blockIdx.x * 256 + threadIdx.x] = 0xFF800000ull;  // m=-inf, s=0
}

// ---------------------------------------------------------------------------
// Kernel T: h_i,h_j [1024][8192] fp32 -> HT [16384][1024] bf16 (transposed)
// ---------------------------------------------------------------------------
__global__ void nt_xent_transpose(const float* __restrict__ hi,
                                  const float* __restrict__ hj,
                                  unsigned short* __restrict__ HT) {
  __shared__ unsigned short tile[64][65];
  const int bn = blockIdx.x, bd = blockIdx.y;
  const int n0 = bn * 64, d0 = bd * 64;
  const float* src = (n0 < NC) ? hi : hj;
  const int nb = (n0 < NC) ? n0 : n0 - NC;
  const int tid = threadIdx.x;
#pragma unroll
  for (int i = 0; i < 16; ++i) {
    int idx = tid + 256 * i;
    int dl = idx >> 6, nl = idx & 63;
    float f = src[(size_t)(d0 + dl) * NC + nb + nl];
    tile[nl][dl] = f2bf(f);
  }
  __syncthreads();
#pragma unroll
  for (int i = 0; i < 16; ++i) {
    int idx = tid + 256 * i;
    int nl = idx >> 6, dl = idx & 63;
    HT[(size_t)(n0 + nl) * FD + d0 + dl] = tile[nl][dl];
  }
}

// ---------------------------------------------------------------------------
// Kernel G: PERSISTENT 256x256-tile symmetric SYRK, deep-pipelined 4-phase
//   K-tiles (counted vmcnt(4), setprio), pipeline maintained ACROSS tiles.
//   Grid = 256 blocks (1/CU), block walks p = slot + 32*r (r=0..8, p<260)
//   of its XCD's 260-tile supertiled triangle list. Tile K-tile 15 stages the
//   NEXT tile's K0; the LSE epilogue lives in spare LDS (no pipeline drain).
//   512 thr = 8 waves (wr: 128-row half, wc: 64-col strip); acc[8][4] f32x4.
//   LDS: 2 buf x (A 32K | B 32K) = 128K @0; red 8K @131072; redc 4K @139264.
//   Frag-linear LDS (zero bank conflicts, measured): frag f = 1KB slot,
//   lane l: row f*16+(l&15), k-half kk, k = kk*32+(l>>4)*8.
//   C/D layout (verified): col = lane&15, row = (lane>>4)*4 + reg.
// ---------------------------------------------------------------------------
__global__ __launch_bounds__(512, 1)
void nt_xent_gemm_lse(const unsigned short* __restrict__ HT,
                      unsigned long long* __restrict__ G) {
  __shared__ __align__(16) unsigned char lds[143360];

  const int tid = threadIdx.x;
  const int w = tid >> 6, l = tid & 63;
  const int lr = l & 15;
  const int lk = (l >> 4) * 8;
  const int wr = w >> 2, wc = w & 3;

  const int xcd = blockIdx.x & 7;
  const int slot = blockIdx.x >> 3;      // 0..31

// stage both frags of one group for a K-tile: dst buf DBUF, k-half KK, A/B ISB
#define STAGE2(AB, BB, KO, DBUF, KK, ISB) do {                               \
    const unsigned short* _s = (ISB) ? (BB) : (AB);                          \
    unsigned char* _d = lds + (DBUF) * 65536 + (ISB) * 32768 +               \
                        (KK) * 16384 + (2 * w) * 1024;                       \
    const int _ko = (KO) + (KK) * 32 + lk;                                   \
    gld16(_s + (((size_t)(2 * w * 16 + lr)) << 10) + _ko, _d);               \
    gld16(_s + (((size_t)((2 * w + 1) * 16 + lr)) << 10) + _ko, _d + 1024);  \
  } while (0)

#define RDA(BUF, KK, MI) \
  (*(const bf16x8*)(lds + (BUF) * 65536 + (KK) * 16384 + (wr * 8 + (MI)) * 1024 + l * 16))
#define RDB(BUF, KK, N) \
  (*(const bf16x8*)(lds + (BUF) * 65536 + 32768 + (KK) * 16384 + (wc * 4 + (N)) * 1024 + l * 16))

#define MFMA16(MB)                                                           \
  _Pragma("unroll") for (int m = 0; m < 4; ++m)                              \
  _Pragma("unroll") for (int n = 0; n < 4; ++n)                              \
    acc[(MB) + m][n] = __builtin_amdgcn_mfma_f32_16x16x32_bf16(              \
        av[m], bv[n], acc[(MB) + m][n], 0, 0, 0);

#define VM4 asm volatile("s_waitcnt vmcnt(4)" ::: "memory")
#define BARW do { __builtin_amdgcn_s_barrier();                              \
    asm volatile("s_waitcnt lgkmcnt(0)" ::: "memory");                       \
    __builtin_amdgcn_sched_barrier(0); } while (0)

// one K-tile (buffer BUF), staging the FOLLOWING K-tile (bases NA/NB, k-off NKO)
#define KTILE(BUF, NA, NB, NKO) do {                                         \
    bv[0] = RDB(BUF, 0, 0); bv[1] = RDB(BUF, 0, 1);                          \
    bv[2] = RDB(BUF, 0, 2); bv[3] = RDB(BUF, 0, 3);                          \
    av[0] = RDA(BUF, 0, 0); av[1] = RDA(BUF, 0, 1);                          \
    av[2] = RDA(BUF, 0, 2); av[3] = RDA(BUF, 0, 3);                          \
    STAGE2(NA, NB, NKO, (BUF) ^ 1, 0, 0);                                    \
    BARW;                                                                    \
    __builtin_amdgcn_s_setprio(1); MFMA16(0) __builtin_amdgcn_s_setprio(0);  \
    __builtin_amdgcn_s_barrier();                                            \
    av[0] = RDA(BUF, 0, 4); av[1] = RDA(BUF, 0, 5);                          \
    av[2] = RDA(BUF, 0, 6); av[3] = RDA(BUF, 0, 7);                          \
    STAGE2(NA, NB, NKO, (BUF) ^ 1, 0, 1);                                    \
    VM4;                                                                     \
    BARW;                                                                    \
    __builtin_amdgcn_s_setprio(1); MFMA16(4) __builtin_amdgcn_s_setprio(0);  \
    __builtin_amdgcn_s_barrier();                                            \
    bv[0] = RDB(BUF, 1, 0); bv[1] = RDB(BUF, 1, 1);                          \
    bv[2] = RDB(BUF, 1, 2); bv[3] = RDB(BUF, 1, 3);                          \
    av[0] = RDA(BUF, 1, 0); av[1] = RDA(BUF, 1, 1);                          \
    av[2] = RDA(BUF, 1, 2); av[3] = RDA(BUF, 1, 3);                          \
    STAGE2(NA, NB, NKO, (BUF) ^ 1, 1, 0);                                    \
    BARW;                                                                    \
    __builtin_amdgcn_s_setprio(1); MFMA16(0) __builtin_amdgcn_s_setprio(0);  \
    __builtin_amdgcn_s_barrier();                                            \
    av[0] = RDA(BUF, 1, 4); av[1] = RDA(BUF, 1, 5);                          \
    av[2] = RDA(BUF, 1, 6); av[3] = RDA(BUF, 1, 7);                          \
    STAGE2(NA, NB, NKO, (BUF) ^ 1, 1, 1);                                    \
    VM4;                                                                     \
    BARW;                                                                    \
    __builtin_amdgcn_s_setprio(1); MFMA16(4) __builtin_amdgcn_s_setprio(0);  \
    __builtin_amdgcn_s_barrier();                                            \
  } while (0)

  f32x4 acc[8][4];
#pragma unroll
  for (int a = 0; a < 8; ++a)
#pragma unroll
    for (int b = 0; b < 4; ++b) acc[a][b] = (f32x4){0.f, 0.f, 0.f, 0.f};
  bf16x8 av[4], bv[4];

  // ---- first tile + prologue: stage its K-tile 0 into buf0, full wait ----
  int p = slot, ti, tj;
  decode_tile(xcd, p, ti, tj);
  const unsigned short* Acur = HT + (((size_t)ti) << 18);
  const unsigned short* Bcur = HT + (((size_t)tj) << 18);
  STAGE2(Acur, Bcur, 0, 0, 0, 0);
  STAGE2(Acur, Bcur, 0, 0, 0, 1);
  STAGE2(Acur, Bcur, 0, 0, 1, 0);
  STAGE2(Acur, Bcur, 0, 0, 1, 1);
  asm volatile("s_waitcnt vmcnt(0)" ::: "memory");
  __builtin_amdgcn_s_barrier();

  while (true) {
    // pre-decode next tile (dummy = tile(0,0): valid addresses, never read)
    const int pn = p + 32;
    const bool has_next = (pn < 260);
    int tin = 0, tjn = 0;
    if (has_next) decode_tile(xcd, pn, tin, tjn);
    const unsigned short* Anx = HT + (((size_t)tin) << 18);
    const unsigned short* Bnx = HT + (((size_t)tjn) << 18);

    // ---- 16 K-tiles; T=0..14 stage same tile, T=15 stages next tile K0 ----
#pragma unroll 1
    for (int Tp = 0; Tp < 7; ++Tp) {
      KTILE(0, Acur, Bcur, (2 * Tp + 1) * 64);
      KTILE(1, Acur, Bcur, (2 * Tp + 2) * 64);
    }
    KTILE(0, Acur, Bcur, 15 * 64);
    KTILE(1, Anx, Bnx, 0);

    // ---- epilogue in spare LDS (no pipeline drain) ----
    {
      float (*red)[4][128][2] = (float (*)[4][128][2])(lds + 131072);
      float (*redc)[2][64][2] = (float (*)[2][64][2])(lds + 139264);
      const int gr0 = ti * 256 + wr * 128 + ((l >> 4) << 2);
      const int gc0 = tj * 256 + wc * 64 + lr;
#pragma unroll
      for (int m = 0; m < 8; ++m) {
#pragma unroll
        for (int rg = 0; rg < 4; ++rg) {
          const int grow = gr0 + m * 16 + rg;
          float vs[4];
          float mx = -INFINITY;
#pragma unroll
          for (int n = 0; n < 4; ++n) {
            float v = acc[m][n][rg] * 2.0f;            // 1/T = 2
            if (gc0 + n * 16 == grow) v = -INFINITY;   // mask diagonal
            vs[n] = v;
            mx = fmaxf(mx, v);
          }
#pragma unroll
          for (int off = 1; off < 16; off <<= 1) mx = fmaxf(mx, __shfl_xor(mx, off, 16));
          float sm = 0.f;
#pragma unroll
          for (int n = 0; n < 4; ++n) sm += __expf(vs[n] - mx);
#pragma unroll
          for (int off = 1; off < 16; off <<= 1) sm += __shfl_xor(sm, off, 16);
          if (lr == 0) {
            const int rl = m * 16 + ((l >> 4) << 2) + rg;   // 0..127
            red[wr][wc][rl][0] = mx;
            red[wr][wc][rl][1] = sm;
          }
        }
      }
      if (ti != tj) {
#pragma unroll
        for (int n = 0; n < 4; ++n) {
          float mx = -INFINITY;
#pragma unroll
          for (int m = 0; m < 8; ++m)
#pragma unroll
            for (int rg = 0; rg < 4; ++rg) mx = fmaxf(mx, acc[m][n][rg] * 2.0f);
          mx = fmaxf(mx, __shfl_xor(mx, 16));
          mx = fmaxf(mx, __shfl_xor(mx, 32));
          float sm = 0.f;
#pragma unroll
          for (int m = 0; m < 8; ++m)
#pragma unroll
            for (int rg = 0; rg < 4; ++rg) sm += __expf(acc[m][n][rg] * 2.0f - mx);
          sm += __shfl_xor(sm, 16);
          sm += __shfl_xor(sm, 32);
          if (l < 16) {
            redc[wc][wr][n * 16 + lr][0] = mx;
            redc[wc][wr][n * 16 + lr][1] = sm;
          }
        }
      }
      // reset accumulators for next tile
#pragma unroll
      for (int a = 0; a < 8; ++a)
#pragma unroll
        for (int b = 0; b < 4; ++b) acc[a][b] = (f32x4){0.f, 0.f, 0.f, 0.f};

      asm volatile("s_waitcnt lgkmcnt(0)" ::: "memory");
      __builtin_amdgcn_s_barrier();

      if (tid < 256) {
        const int row = tid, wrr = row >> 7, rl = row & 127;
        float M = -INFINITY;
#pragma unroll
        for (int c = 0; c < 4; ++c) M = fmaxf(M, red[wrr][c][rl][0]);
        float S = 0.f;
#pragma unroll
        for (int c = 0; c < 4; ++c) S += red[wrr][c][rl][1] * __expf(red[wrr][c][rl][0] - M);
        cas_merge(&G[ti * 256 + row], M, S);
      } else if (ti != tj) {
        const int col = tid - 256, wcc = col >> 6, cl = col & 63;
        float m0 = redc[wcc][0][cl][0], s0 = redc[wcc][0][cl][1];
        float m1 = redc[wcc][1][cl][0], s1 = redc[wcc][1][cl][1];
        float mn = fmaxf(m0, m1);
        float s = s0 * __expf(m0 - mn) + s1 * __expf(m1 - mn);
        cas_merge(&G[tj * 256 + col], mn, s);
      }
      __builtin_amdgcn_s_barrier();
    }

    if (!has_next) break;
    p = pn; ti = tin; tj = tjn; Acur = Anx; Bcur = Bnx;
  }

#undef STAGE2
#undef RDA
#undef RDB
#undef MFMA16
#undef VM4
#undef BARW
#undef KTILE
}

// ---------------------------------------------------------------------------
// Kernel F: lse[i] = m + log(s); pos = 2*dot(HT[i],HT[partner]);
//           out += (lse - pos)/NT
// ---------------------------------------------------------------------------
__global__ void nt_xent_final(const unsigned short* __restrict__ HT,
                              const unsigned long long* __restrict__ G,
                              float* __restrict__ out) {
  const int tid = threadIdx.x;
  const int w = tid >> 6, l = tid & 63;
  const int wave = blockIdx.x * 4 + w;      // 0..1023, 16 rows each
  float local = 0.f;
  for (int rr = 0; rr < 16; ++rr) {
    int i = wave * 16 + rr;
    int p = (i + NC) & (NT - 1);
    const int4* A = (const int4*)(HT + (((size_t)i) << 10) + (l << 4));
    const int4* B = (const int4*)(HT + (((size_t)p) << 10) + (l << 4));
    union { int4 v; unsigned short u[8]; } a0, a1, b0, b1;
    a0.v = A[0]; a1.v = A[1]; b0.v = B[0]; b1.v = B[1];
    float dot = 0.f;
#pragma unroll
    for (int j = 0; j < 8; ++j) dot += bf2f(a0.u[j]) * bf2f(b0.u[j]);
#pragma unroll
    for (int j = 0; j < 8; ++j) dot += bf2f(a1.u[j]) * bf2f(b1.u[j]);
#pragma unroll
    for (int off = 1; off < 64; off <<= 1) dot += __shfl_xor(dot, off, 64);
    if (l == 0) {
      unsigned long long g = G[i];
      float m = __uint_as_float((unsigned)(g & 0xffffffffull));
      float s = __uint_as_float((unsigned)(g >> 32));
      local += m + __logf(s) - 2.0f * dot;
    }
  }
  if (l == 0) atomicAdd(out, local * (1.0f / (float)NT));
}

// ---------------------------------------------------------------------------
extern "C" void kernel_launch(void* const* d_in, const int* in_sizes, int n_in,
                              void* d_out, int out_size, void* d_ws, size_t ws_size,
                              hipStream_t stream) {
  const float* hi = (const float*)d_in[0];
  const float* hj = (const float*)d_in[1];
  unsigned short* HT = (unsigned short*)d_ws;
  unsigned long long* G = (unsigned long long*)((char*)d_ws + (size_t)NT * FD * 2);
  float* out = (float*)d_out;

  const size_t need = (size_t)NT * FD * 2 + (size_t)NT * 8;
  if (ws_size < need) return;

  hipMemsetAsync(out, 0, sizeof(float), stream);
  nt_xent_init<<<NT / 256, 256, 0, stream>>>(G);
  nt_xent_transpose<<<dim3(NT / 64, FD / 64), 256, 0, stream>>>(hi, hj, HT);
  nt_xent_gemm_lse<<<256, 512, 0, stream>>>(HT, G);
  nt_xent_final<<<NT / 64, 256, 0, stream>>>(HT, G, out);
}